// Round 2
// baseline (2155.602 us; speedup 1.0000x reference)
//
#include <hip/hip_runtime.h>
#include <hip/hip_bf16.h>
#include <stdint.h>
#include <stddef.h>

// QDGAT forward, MI355X gfx950.
// Round 2: inputs/outputs are fp32 (per reference dtypes). Internal GEMMs use
// bf16 MFMA (2% absmax budget): convert ents + weight matrices to bf16 scratch
// once per launch; biases / pk / pv / wes / mask stay fp32 in VALU epilogues.

typedef __hip_bfloat16 bf16;
typedef __attribute__((ext_vector_type(8))) short short8;
typedef __attribute__((ext_vector_type(4))) float floatx4;

#define NB 4
#define NN 1024
#define DD 1024
#define NT_ITER 4
#define MM (NB * NN) // 4096

static __device__ __forceinline__ float b2f(bf16 x) { return __bfloat162float(x); }
static __device__ __forceinline__ bf16 f2b(float x) { return __float2bfloat16(x); }
static __device__ __forceinline__ unsigned short f2bu(float x) {
    bf16 h = __float2bfloat16(x);
    unsigned short u;
    __builtin_memcpy(&u, &h, 2);
    return u;
}

// ---------------------------------------------------------------------------
// fp32 -> bf16 conversion, 4 elements/thread.
// ---------------------------------------------------------------------------
__global__ void k_f2b(const float* __restrict__ src, bf16* __restrict__ dst, int n4) {
    int i = blockIdx.x * 256 + threadIdx.x;
    if (i >= n4) return;
    float4 v = ((const float4*)src)[i];
    ushort4 o;
    o.x = f2bu(v.x); o.y = f2bu(v.y); o.z = f2bu(v.z); o.w = f2bu(v.w);
    ((ushort4*)dst)[i] = o;
}

// ---------------------------------------------------------------------------
// Small dense layers (few rows): one thread per output element, fp32.
// ---------------------------------------------------------------------------
__global__ void k_qbase(const float* __restrict__ qenc, const float* __restrict__ w,
                        const float* __restrict__ b, float* __restrict__ out) {
    int idx = blockIdx.x * 256 + threadIdx.x; // NB*DD = 4096
    if (idx >= NB * DD) return;
    int r = idx >> 10, n = idx & 1023;
    const float* xr = qenc + (size_t)r * DD;
    const float* wr = w + (size_t)n * DD;
    float s = b[n];
    for (int d = 0; d < DD; ++d) s += xr[d] * wr[d];
    out[idx] = s > 0.f ? s : (expf(s) - 1.0f); // ELU(alpha=1)
}

__global__ void k_cmd(const float* __restrict__ qb, const float* __restrict__ w_qt,
                      const float* __restrict__ b_qt, float* __restrict__ cmd) {
    int idx = blockIdx.x * 256 + threadIdx.x; // NT*NB*DD = 16384
    if (idx >= NT_ITER * NB * DD) return;
    int t = idx >> 12;
    int r = (idx >> 10) & 3;
    int n = idx & 1023;
    const float* xr = qb + (size_t)r * DD;
    const float* wr = w_qt + ((size_t)t * DD + n) * DD;
    float s = b_qt[t * DD + n];
    for (int d = 0; d < DD; ++d) s += xr[d] * wr[d];
    cmd[idx] = s;
}

__global__ void k_pkpv(const float* __restrict__ cmd,
                       const float* __restrict__ w_pk, const float* __restrict__ b_pk,
                       const float* __restrict__ w_pv, const float* __restrict__ b_pv,
                       float* __restrict__ pk, float* __restrict__ pv) {
    int idx = blockIdx.x * 256 + threadIdx.x; // 2*NT*NB*DD = 32768
    if (idx >= 2 * NT_ITER * NB * DD) return;
    int half = idx >> 14;
    int j = idx & 16383;
    int n = j & 1023;
    const float* xr = cmd + (size_t)(j >> 10) * DD;
    const float* w = half ? w_pv : w_pk;
    const float* bb = half ? b_pv : b_pk;
    const float* wr = w + (size_t)n * DD;
    float s = bb[n];
    for (int d = 0; d < DD; ++d) s += xr[d] * wr[d];
    (half ? pv : pk)[j] = s;
}

// ---------------------------------------------------------------------------
// Elementwise
// ---------------------------------------------------------------------------
__global__ void k_init_xctx(const float* __restrict__ initm, bf16* __restrict__ x_ctx) {
    size_t idx = (size_t)blockIdx.x * 256 + threadIdx.x; // MM*DD
    x_ctx[idx] = f2b(initm[idx & 1023]);
}

__global__ void k_xc(const bf16* __restrict__ x_ctx, const float* __restrict__ mask,
                     bf16* __restrict__ xc) {
    size_t idx = (size_t)blockIdx.x * 256 + threadIdx.x; // MM*DD
    xc[idx] = f2b(b2f(x_ctx[idx]) * mask[idx >> 10]);
}

// ---------------------------------------------------------------------------
// Main MFMA GEMM.  C[m,n] = sum over chunks c of A_c[m,k] * W[n, c*1024+k]
//  + bias[n], optional epilogue multiply, bf16 or fp32 store.
// Tile 64x64, BK=64. 4 waves, each 32x32 (2x2 of 16x16x32 MFMA).
// mulmode: 0 none, 1 bf16 mul[m*1024+n], 2 row-broadcast f32 mul[(m>>10)*1024+n]
// ---------------------------------------------------------------------------
__global__ __launch_bounds__(256) void k_gemm(
    const bf16* __restrict__ A0, const bf16* __restrict__ A1, const bf16* __restrict__ A2,
    const bf16* __restrict__ W, const float* __restrict__ bias,
    void* __restrict__ C, const void* __restrict__ mul, int mulmode, int storef32,
    int nchunks, int ldw, long long sA, long long sW, long long sC) {
    __shared__ bf16 sAt[64 * 64];
    __shared__ bf16 sWt[64 * 64];

    const int t = threadIdx.x;
    const int lane = t & 63;
    const int w = t >> 6;
    const int wm = (w & 1) * 32, wn = (w >> 1) * 32;
    const int bm = blockIdx.x, bn = blockIdx.y, bz = blockIdx.z;

    const bf16* A0b = A0 + (size_t)bz * sA;
    const bf16* Wb = W + (size_t)bz * sW;

    floatx4 acc[2][2];
#pragma unroll
    for (int i = 0; i < 2; ++i)
#pragma unroll
        for (int j = 0; j < 2; ++j) acc[i][j] = (floatx4){0.f, 0.f, 0.f, 0.f};

    const int lrow = lane & 15;
    const int kq = (lane >> 4) * 8;
    const int ktiles = nchunks * 16;

    for (int kt = 0; kt < ktiles; ++kt) {
        const int cidx = kt >> 4;
        const bf16* Ac = (cidx == 0) ? A0b : (cidx == 1 ? A1 : A2);
        const int klocal = (kt & 15) * 64;
        const int kglob = kt * 64;
#pragma unroll
        for (int i = 0; i < 4; ++i) {
            int id = t + i * 256;
            int row = (id >> 3) & 63;
            int c8 = id & 7;
            if (id < 512) {
                const uint4* src = (const uint4*)(Ac + ((size_t)(bm * 64 + row)) * 1024 + klocal + c8 * 8);
                *(uint4*)(&sAt[row * 64 + c8 * 8]) = *src;
            } else {
                const uint4* src = (const uint4*)(Wb + ((size_t)(bn * 64 + row)) * (size_t)ldw + kglob + c8 * 8);
                *(uint4*)(&sWt[row * 64 + c8 * 8]) = *src;
            }
        }
        __syncthreads();
#pragma unroll
        for (int ks = 0; ks < 2; ++ks) {
            const int ko = ks * 32 + kq;
            short8 af[2], bfr[2];
            af[0] = *(const short8*)&sAt[(wm + lrow) * 64 + ko];
            af[1] = *(const short8*)&sAt[(wm + 16 + lrow) * 64 + ko];
            bfr[0] = *(const short8*)&sWt[(wn + lrow) * 64 + ko];
            bfr[1] = *(const short8*)&sWt[(wn + 16 + lrow) * 64 + ko];
#pragma unroll
            for (int mi = 0; mi < 2; ++mi)
#pragma unroll
                for (int ni = 0; ni < 2; ++ni)
                    acc[mi][ni] = __builtin_amdgcn_mfma_f32_16x16x32_bf16(af[mi], bfr[ni], acc[mi][ni], 0, 0, 0);
        }
        __syncthreads();
    }

    const int qrow = (lane >> 4) * 4;
#pragma unroll
    for (int mi = 0; mi < 2; ++mi) {
#pragma unroll
        for (int ni = 0; ni < 2; ++ni) {
            int gn = bn * 64 + wn + ni * 16 + lrow;
            float bv = bias ? bias[gn] : 0.f;
#pragma unroll
            for (int r = 0; r < 4; ++r) {
                int gm = bm * 64 + wm + mi * 16 + qrow + r;
                float val = acc[mi][ni][r] + bv;
                if (mulmode == 1)
                    val *= b2f(((const bf16*)mul)[(size_t)gm * 1024 + gn]);
                else if (mulmode == 2)
                    val *= ((const float*)mul)[(size_t)(gm >> 10) * 1024 + gn];
                size_t ci = (size_t)bz * sC + (size_t)gm * 1024 + gn;
                if (storef32)
                    ((float*)C)[ci] = val;
                else
                    ((bf16*)C)[ci] = f2b(val);
            }
        }
    }
}

// ---------------------------------------------------------------------------
// v (B,N,D) -> vT (B,D,N)
// ---------------------------------------------------------------------------
__global__ void k_transpose(const bf16* __restrict__ v, bf16* __restrict__ vT) {
    __shared__ bf16 tile[32][33];
    int b = blockIdx.z;
    int n0 = blockIdx.x * 32, d0 = blockIdx.y * 32;
    int tx = threadIdx.x, ty = threadIdx.y; // (32,8)
    for (int i = 0; i < 32; i += 8)
        tile[ty + i][tx] = v[((size_t)b * NN + n0 + ty + i) * DD + d0 + tx];
    __syncthreads();
    for (int i = 0; i < 32; i += 8)
        vT[((size_t)b * DD + d0 + ty + i) * NN + n0 + tx] = tile[tx][ty + i];
}

// ---------------------------------------------------------------------------
// qa[m,e] = q[m,:] . wes[e,0:D]; kb[m,e] = k[m,:] . wes[e,D:2D]; e=0..3
// ---------------------------------------------------------------------------
__global__ __launch_bounds__(256) void k_qakb(const bf16* __restrict__ q, const bf16* __restrict__ k,
                                              const float* __restrict__ wes,
                                              float* __restrict__ qa, float* __restrict__ kb) {
    __shared__ float red[4];
    int m = blockIdx.x;
    int t = threadIdx.x;
    float pq[4] = {0.f, 0.f, 0.f, 0.f}, pk[4] = {0.f, 0.f, 0.f, 0.f};
    const bf16* qr = q + (size_t)m * DD;
    const bf16* kr = k + (size_t)m * DD;
    for (int d = t; d < DD; d += 256) {
        float qd = b2f(qr[d]);
        float kd = b2f(kr[d]);
#pragma unroll
        for (int e = 0; e < 4; ++e) {
            pq[e] += qd * wes[e * 2048 + d];
            pk[e] += kd * wes[e * 2048 + 1024 + d];
        }
    }
    for (int e = 0; e < 8; ++e) {
        float v = (e < 4) ? pq[e] : pk[e - 4];
        for (int o = 32; o > 0; o >>= 1) v += __shfl_down(v, o);
        if ((t & 63) == 0) red[t >> 6] = v;
        __syncthreads();
        if (t == 0) {
            float s = red[0] + red[1] + red[2] + red[3];
            (e < 4 ? qa : kb)[(size_t)m * 4 + (e & 3)] = s;
        }
        __syncthreads();
    }
}

// ---------------------------------------------------------------------------
// Edge scores + masked softmax: one block per (b,i) row.
// ---------------------------------------------------------------------------
__global__ __launch_bounds__(256) void k_attn(const int* __restrict__ adj, const float* __restrict__ qa,
                                              const float* __restrict__ kb, const int* __restrict__ typesPtr,
                                              bf16* __restrict__ prob) {
    __shared__ float lg[NN];
    __shared__ float red[4];
    __shared__ float red2[4];
    int m = blockIdx.x; // b*N + i
    int b = m >> 10;
    int t = threadIdx.x;
    int types = typesPtr[0];
    float qa4[4];
#pragma unroll
    for (int e = 0; e < 4; ++e) qa4[e] = qa[(size_t)m * 4 + e];
    const int* arow = adj + (size_t)m * NN;
    const float* kbb = kb + (size_t)(b << 10) * 4;

    float lmax = -3.0e38f;
    for (int j = t; j < NN; j += 256) {
        int a = arow[j];
        float l;
        if (a == 0) {
            l = -9.0e15f;
        } else if ((types >> a) & 1) {
            float s = qa4[a - 1] + kbb[(size_t)j * 4 + (a - 1)];
            l = s > 0.f ? s : 0.2f * s;
        } else {
            l = 0.f;
        }
        lg[j] = l;
        lmax = fmaxf(lmax, l);
    }
    for (int o = 32; o > 0; o >>= 1) lmax = fmaxf(lmax, __shfl_down(lmax, o));
    if ((t & 63) == 0) red[t >> 6] = lmax;
    __syncthreads();
    lmax = fmaxf(fmaxf(red[0], red[1]), fmaxf(red[2], red[3]));

    float lsum = 0.f;
    for (int j = t; j < NN; j += 256) {
        float ex = expf(lg[j] - lmax);
        lg[j] = ex;
        lsum += ex;
    }
    for (int o = 32; o > 0; o >>= 1) lsum += __shfl_down(lsum, o);
    if ((t & 63) == 0) red2[t >> 6] = lsum;
    __syncthreads();
    lsum = red2[0] + red2[1] + red2[2] + red2[3];
    float inv = 1.0f / lsum;

    bf16* prow = prob + (size_t)m * NN;
    for (int j = t; j < NN; j += 256) prow[j] = f2b(lg[j] * inv);
}

// ---------------------------------------------------------------------------
extern "C" void kernel_launch(void* const* d_in, const int* in_sizes, int n_in,
                              void* d_out, int out_size, void* d_ws, size_t ws_size,
                              hipStream_t stream) {
    const float* ents = (const float*)d_in[0];
    const float* mask = (const float*)d_in[1];
    const float* qenc = (const float*)d_in[2];
    const int* adj = (const int*)d_in[3];
    const int* types = (const int*)d_in[4];
    const float* initm = (const float*)d_in[5];
    const float* w_qin = (const float*)d_in[6];
    const float* b_qin = (const float*)d_in[7];
    const float* w_qt = (const float*)d_in[8];
    const float* b_qt = (const float*)d_in[9];
    const float* w_pl = (const float*)d_in[10];
    const float* b_pl = (const float*)d_in[11];
    const float* w_pc = (const float*)d_in[12];
    const float* b_pc = (const float*)d_in[13];
    const float* w_q = (const float*)d_in[14];
    const float* b_q = (const float*)d_in[15];
    const float* w_k = (const float*)d_in[16];
    const float* b_k = (const float*)d_in[17];
    const float* w_v = (const float*)d_in[18];
    const float* b_v = (const float*)d_in[19];
    const float* w_pk = (const float*)d_in[20];
    const float* b_pk = (const float*)d_in[21];
    const float* w_pv = (const float*)d_in[22];
    const float* b_pv = (const float*)d_in[23];
    const float* wes = (const float*)d_in[24];
    const float* w_mu = (const float*)d_in[25];
    const float* b_mu = (const float*)d_in[26];
    const float* w_cb = (const float*)d_in[27];
    const float* b_cb = (const float*)d_in[28];
    (void)in_sizes; (void)n_in; (void)out_size; (void)ws_size;

    char* p = (char*)d_ws;
    auto carve = [&](size_t bytes) {
        char* r = p;
        p += (bytes + 255) & ~(size_t)255;
        return r;
    };
    // fp32 smalls
    float* q_base = (float*)carve((size_t)NB * DD * 4);
    float* cmd = (float*)carve((size_t)NT_ITER * NB * DD * 4);
    float* pk = (float*)carve((size_t)NT_ITER * NB * DD * 4);
    float* pv = (float*)carve((size_t)NT_ITER * NB * DD * 4);
    float* qa = (float*)carve((size_t)MM * 4 * 4);
    float* kb = (float*)carve((size_t)MM * 4 * 4);
    // bf16 weight copies
    bf16* ents_bf = (bf16*)carve((size_t)MM * DD * 2);
    bf16* wpl_bf = (bf16*)carve((size_t)DD * DD * 2);
    bf16* wpc_bf = (bf16*)carve((size_t)DD * DD * 2);
    bf16* wq_bf = (bf16*)carve((size_t)DD * 3 * DD * 2);
    bf16* wk_bf = (bf16*)carve((size_t)DD * 3 * DD * 2);
    bf16* wv_bf = (bf16*)carve((size_t)DD * 3 * DD * 2);
    bf16* wmu_bf = (bf16*)carve((size_t)DD * 2 * DD * 2);
    bf16* wcb_bf = (bf16*)carve((size_t)DD * 2 * DD * 2);
    // bf16 activations (with aliasing of dead buffers)
    bf16* x_ctx = (bf16*)carve((size_t)MM * DD * 2);
    bf16* xc = (bf16*)carve((size_t)MM * DD * 2);
    bf16* pl = (bf16*)carve((size_t)MM * DD * 2);
    bf16* plpc = (bf16*)carve((size_t)MM * DD * 2); // also vT after q/k/v GEMMs
    bf16* qb = (bf16*)carve((size_t)MM * DD * 2);   // also msg after k_qakb
    bf16* kbuf = (bf16*)carve((size_t)MM * DD * 2);
    bf16* vbuf = (bf16*)carve((size_t)MM * DD * 2); // also prob after transpose
    bf16* vT = plpc;
    bf16* msg = qb;
    bf16* prob = vbuf;

    const dim3 blk(256);
    const dim3 gBig(64, 16, 1);  // M=4096 x Nout=1024, 64x64 tiles
    const dim3 gMsg(16, 16, NB); // per-batch M=1024

    // fp32 -> bf16 conversions (once per launch)
    k_f2b<<<4096, blk, 0, stream>>>(ents, ents_bf, MM * DD / 4);
    k_f2b<<<1024, blk, 0, stream>>>(w_pl, wpl_bf, DD * DD / 4);
    k_f2b<<<1024, blk, 0, stream>>>(w_pc, wpc_bf, DD * DD / 4);
    k_f2b<<<3072, blk, 0, stream>>>(w_q, wq_bf, DD * 3 * DD / 4);
    k_f2b<<<3072, blk, 0, stream>>>(w_k, wk_bf, DD * 3 * DD / 4);
    k_f2b<<<3072, blk, 0, stream>>>(w_v, wv_bf, DD * 3 * DD / 4);
    k_f2b<<<2048, blk, 0, stream>>>(w_mu, wmu_bf, DD * 2 * DD / 4);
    k_f2b<<<2048, blk, 0, stream>>>(w_cb, wcb_bf, DD * 2 * DD / 4);

    k_qbase<<<16, blk, 0, stream>>>(qenc, w_qin, b_qin, q_base);
    k_cmd<<<64, blk, 0, stream>>>(q_base, w_qt, b_qt, cmd);
    k_pkpv<<<128, blk, 0, stream>>>(cmd, w_pk, b_pk, w_pv, b_pv, pk, pv);
    k_init_xctx<<<16384, blk, 0, stream>>>(initm, x_ctx);

    // pl = ents @ w_pl.T + b_pl  (loop-invariant)
    k_gemm<<<gBig, blk, 0, stream>>>(ents_bf, nullptr, nullptr, wpl_bf, b_pl, pl,
                                     nullptr, 0, 0, 1, 1024, 0, 0, 0);

    for (int t = 0; t < NT_ITER; ++t) {
        k_xc<<<16384, blk, 0, stream>>>(x_ctx, mask, xc);
        // plpc = (xc @ w_pc.T + b_pc) * pl
        k_gemm<<<gBig, blk, 0, stream>>>(xc, nullptr, nullptr, wpc_bf, b_pc, plpc,
                                         pl, 1, 0, 1, 1024, 0, 0, 0);
        // q = x_joint @ w_q.T + b_q   (x_joint = [ents, xc, plpc])
        k_gemm<<<gBig, blk, 0, stream>>>(ents_bf, xc, plpc, wq_bf, b_q, qb,
                                         nullptr, 0, 0, 3, 3072, 0, 0, 0);
        // k = (x_joint @ w_k.T + b_k) * pk[t,b,:]
        k_gemm<<<gBig, blk, 0, stream>>>(ents_bf, xc, plpc, wk_bf, b_k, kbuf,
                                         pk + (size_t)t * NB * DD, 2, 0, 3, 3072, 0, 0, 0);
        // v = (x_joint @ w_v.T + b_v) * pv[t,b,:]
        k_gemm<<<gBig, blk, 0, stream>>>(ents_bf, xc, plpc, wv_bf, b_v, vbuf,
                                         pv + (size_t)t * NB * DD, 2, 0, 3, 3072, 0, 0, 0);
        k_qakb<<<4096, blk, 0, stream>>>(qb, kbuf, wes, qa, kb);
        k_transpose<<<dim3(32, 32, NB), dim3(32, 8), 0, stream>>>(vbuf, vT);
        k_attn<<<4096, blk, 0, stream>>>(adj, qa, kb, types, prob);
        // message[b] = prob[b] @ vT[b]^T
        k_gemm<<<gMsg, blk, 0, stream>>>(prob, nullptr, nullptr, vT, nullptr, msg,
                                         nullptr, 0, 0, 1, 1024,
                                         (long long)NN * NN, (long long)DD * NN, (long long)NN * DD);
        // x_ctx = [xc, msg] @ w_mu.T + b_mu
        k_gemm<<<gBig, blk, 0, stream>>>(xc, msg, nullptr, wmu_bf, b_mu, x_ctx,
                                         nullptr, 0, 0, 2, 2048, 0, 0, 0);
    }
    // out = [ents, x_ctx] @ w_cb.T + b_cb  (fp32 store)
    k_gemm<<<gBig, blk, 0, stream>>>(ents_bf, x_ctx, nullptr, wcb_bf, b_cb, (float*)d_out,
                                     nullptr, 0, 1, 2, 2048, 0, 0, 0);
}

// Round 3
// 1485.632 us; speedup vs baseline: 1.4510x; 1.4510x over previous
//
#include <hip/hip_runtime.h>
#include <hip/hip_bf16.h>
#include <stdint.h>
#include <stddef.h>

// QDGAT forward, MI355X gfx950.
// Round 3: m97-structure GEMM (128x128 tile, BK=64, global_load_lds width=16,
// 4 waves x 4x4 MFMA 16x16x32), q/k/v fused into one grid.z=3 dispatch,
// coalesced wave-per-output GEMVs, vectorized elementwise kernels.
// Inputs/outputs fp32; internal GEMMs bf16 (verified absmax 0.031 << 0.11).

typedef __hip_bfloat16 bf16;
typedef __attribute__((ext_vector_type(8))) short short8;
typedef __attribute__((ext_vector_type(4))) float floatx4;

#define NB 4
#define NN 1024
#define DD 1024
#define NT_ITER 4
#define MM (NB * NN) // 4096

static __device__ __forceinline__ float b2f(bf16 x) { return __bfloat162float(x); }
static __device__ __forceinline__ bf16 f2b(float x) { return __float2bfloat16(x); }
static __device__ __forceinline__ unsigned short f2bu(float x) {
    bf16 h = __float2bfloat16(x);
    unsigned short u;
    __builtin_memcpy(&u, &h, 2);
    return u;
}
static __device__ __forceinline__ float bu2f(unsigned short u) {
    unsigned int t = (unsigned int)u << 16;
    float f;
    __builtin_memcpy(&f, &t, 4);
    return f;
}

// global -> LDS direct DMA, 16 B per lane. LDS dest = wave-uniform base + lane*16.
static __device__ __forceinline__ void gl_lds16(const void* g, void* l) {
    __builtin_amdgcn_global_load_lds(
        (const __attribute__((address_space(1))) unsigned int*)g,
        (__attribute__((address_space(3))) unsigned int*)l, 16, 0, 0);
}

// ---------------------------------------------------------------------------
// fp32 -> bf16 conversion, 4 elements/thread.
// ---------------------------------------------------------------------------
__global__ void k_f2b(const float* __restrict__ src, bf16* __restrict__ dst, int n4) {
    int i = blockIdx.x * 256 + threadIdx.x;
    if (i >= n4) return;
    float4 v = ((const float4*)src)[i];
    ushort4 o;
    o.x = f2bu(v.x); o.y = f2bu(v.y); o.z = f2bu(v.z); o.w = f2bu(v.w);
    ((ushort4*)dst)[i] = o;
}

// ---------------------------------------------------------------------------
// Wave-per-output GEMVs (coalesced weight-row reads, shuffle reduce).
// ---------------------------------------------------------------------------
__global__ __launch_bounds__(256) void k_qbase(const float* __restrict__ qenc, const float* __restrict__ w,
                                               const float* __restrict__ b, float* __restrict__ out) {
    int o = blockIdx.x * 4 + (threadIdx.x >> 6); // o = n*4 + r; 4096 outputs
    int lane = threadIdx.x & 63;
    int n = o >> 2, r = o & 3;
    const float* xr = qenc + (size_t)r * DD;
    const float* wr = w + (size_t)n * DD;
    float s = 0.f;
    for (int d = lane; d < DD; d += 64) s += xr[d] * wr[d];
    for (int off = 32; off; off >>= 1) s += __shfl_down(s, off);
    if (lane == 0) {
        s += b[n];
        out[(size_t)r * DD + n] = s > 0.f ? s : (expf(s) - 1.0f); // ELU
    }
}

__global__ __launch_bounds__(256) void k_cmd(const float* __restrict__ qb, const float* __restrict__ w_qt,
                                             const float* __restrict__ b_qt, float* __restrict__ cmd) {
    int o = blockIdx.x * 4 + (threadIdx.x >> 6); // o = t*4096 + n*4 + r; 16384
    int lane = threadIdx.x & 63;
    int r = o & 3, n = (o >> 2) & 1023, t = o >> 12;
    const float* xr = qb + (size_t)r * DD;
    const float* wr = w_qt + ((size_t)t * DD + n) * DD;
    float s = 0.f;
    for (int d = lane; d < DD; d += 64) s += xr[d] * wr[d];
    for (int off = 32; off; off >>= 1) s += __shfl_down(s, off);
    if (lane == 0) cmd[((size_t)t * NB + r) * DD + n] = s + b_qt[t * DD + n];
}

__global__ __launch_bounds__(256) void k_pkpv(const float* __restrict__ cmd,
                                              const float* __restrict__ w_pk, const float* __restrict__ b_pk,
                                              const float* __restrict__ w_pv, const float* __restrict__ b_pv,
                                              float* __restrict__ pk, float* __restrict__ pv) {
    int o = blockIdx.x * 4 + (threadIdx.x >> 6); // o = n*32 + half*16 + pair; 32768
    int lane = threadIdx.x & 63;
    int n = o >> 5, half = (o >> 4) & 1, pair = o & 15;
    const float* xr = cmd + (size_t)pair * DD;
    const float* wr = (half ? w_pv : w_pk) + (size_t)n * DD;
    float s = 0.f;
    for (int d = lane; d < DD; d += 64) s += xr[d] * wr[d];
    for (int off = 32; off; off >>= 1) s += __shfl_down(s, off);
    if (lane == 0)
        (half ? pv : pk)[(size_t)pair * DD + n] = s + (half ? b_pv : b_pk)[n];
}

// ---------------------------------------------------------------------------
// Elementwise (16 B / thread)
// ---------------------------------------------------------------------------
__global__ void k_init_xctx(const bf16* __restrict__ initm_bf, bf16* __restrict__ x_ctx) {
    int i = blockIdx.x * 256 + threadIdx.x; // uint4 idx, MM*DD/8 = 524288
    ((uint4*)x_ctx)[i] = ((const uint4*)initm_bf)[i & 127];
}

__global__ void k_xc(const bf16* __restrict__ x_ctx, const float* __restrict__ mask,
                     bf16* __restrict__ xc) {
    int i = blockIdx.x * 256 + threadIdx.x; // 8-elem groups, 524288
    float mk = mask[i >> 7];
    uint4 v = ((const uint4*)x_ctx)[i];
    unsigned short* u = (unsigned short*)&v;
#pragma unroll
    for (int j = 0; j < 8; ++j) u[j] = f2bu(bu2f(u[j]) * mk);
    ((uint4*)xc)[i] = v;
}

// ---------------------------------------------------------------------------
// m97-structure GEMM core: C[m,n] = sum_c A_c[m,k]*W[n,c*1024+k] (+bias)(*mul)
// 128x128 tile, BK=64, 4 waves each 64x64 (4x4 of 16x16x32 MFMA).
// A_c lda=1024 always; W row-major ldw; C ldc=1024.
// mulmode: 0 none, 1 bf16 mul[m*1024+n], 2 f32 mul[(m>>10)*1024+n].
// ---------------------------------------------------------------------------
__device__ __forceinline__ void gemm128_core(
    const bf16* __restrict__ A0, const bf16* __restrict__ A1, const bf16* __restrict__ A2,
    const bf16* __restrict__ W, const float* __restrict__ bias, void* __restrict__ C,
    const void* __restrict__ mul, int mulmode, int storef32, int nchunks, int ldw,
    int bm, int bn) {
    __shared__ bf16 sA[128 * 64];
    __shared__ bf16 sB[128 * 64];

    const int t = threadIdx.x;
    const int lane = t & 63;
    const int w = t >> 6;
    const int wm = (w & 1) * 64, wn = (w >> 1) * 64;
    const int srow = lane >> 3;       // 0..7 within 8-row chunk
    const int scol = (lane & 7) * 8;  // element col within 64

    floatx4 acc[4][4];
#pragma unroll
    for (int i = 0; i < 4; ++i)
#pragma unroll
        for (int j = 0; j < 4; ++j) acc[i][j] = (floatx4){0.f, 0.f, 0.f, 0.f};

    const int lrow = lane & 15;
    const int kq = (lane >> 4) * 8;
    const int ktiles = nchunks * 16;

    for (int kt = 0; kt < ktiles; ++kt) {
        const int cidx = kt >> 4;
        const bf16* Ac = (cidx == 0) ? A0 : (cidx == 1 ? A1 : A2);
        const int klocal = (kt & 15) * 64;
        const int kglob = kt * 64;
        // Stage 32 KB: waves 0,1 -> A (64 rows each), waves 2,3 -> B.
        if (w < 2) {
#pragma unroll
            for (int i = 0; i < 8; ++i) {
                int row = w * 64 + i * 8;
                const bf16* src = Ac + ((size_t)(bm * 128 + row + srow)) * 1024 + klocal + scol;
                gl_lds16(src, &sA[row * 64]);
            }
        } else {
#pragma unroll
            for (int i = 0; i < 8; ++i) {
                int row = (w - 2) * 64 + i * 8;
                const bf16* src = W + ((size_t)(bn * 128 + row + srow)) * (size_t)ldw + kglob + scol;
                gl_lds16(src, &sB[row * 64]);
            }
        }
        __syncthreads();
#pragma unroll
        for (int ks = 0; ks < 2; ++ks) {
            const int ko = ks * 32 + kq;
            short8 af[4], bfr[4];
#pragma unroll
            for (int mi = 0; mi < 4; ++mi) af[mi] = *(const short8*)&sA[(wm + mi * 16 + lrow) * 64 + ko];
#pragma unroll
            for (int ni = 0; ni < 4; ++ni) bfr[ni] = *(const short8*)&sB[(wn + ni * 16 + lrow) * 64 + ko];
#pragma unroll
            for (int mi = 0; mi < 4; ++mi)
#pragma unroll
                for (int ni = 0; ni < 4; ++ni)
                    acc[mi][ni] = __builtin_amdgcn_mfma_f32_16x16x32_bf16(af[mi], bfr[ni], acc[mi][ni], 0, 0, 0);
        }
        __syncthreads();
    }

    const int qrow = (lane >> 4) * 4;
#pragma unroll
    for (int mi = 0; mi < 4; ++mi) {
#pragma unroll
        for (int ni = 0; ni < 4; ++ni) {
            int gn = bn * 128 + wn + ni * 16 + lrow;
            float bv = bias ? bias[gn] : 0.f;
#pragma unroll
            for (int r = 0; r < 4; ++r) {
                int gm = bm * 128 + wm + mi * 16 + qrow + r;
                float val = acc[mi][ni][r] + bv;
                if (mulmode == 1)
                    val *= b2f(((const bf16*)mul)[(size_t)gm * 1024 + gn]);
                else if (mulmode == 2)
                    val *= ((const float*)mul)[(size_t)(gm >> 10) * 1024 + gn];
                size_t ci = (size_t)gm * 1024 + gn;
                if (storef32)
                    ((float*)C)[ci] = val;
                else
                    ((bf16*)C)[ci] = f2b(val);
            }
        }
    }
}

// Generic (optionally z-batched) wrapper.
__global__ __launch_bounds__(256) void k_gemm_b(
    const bf16* __restrict__ A0, const bf16* __restrict__ A1, const bf16* __restrict__ A2,
    const bf16* __restrict__ W, const float* __restrict__ bias, void* __restrict__ C,
    const void* __restrict__ mul, int mulmode, int storef32, int nchunks, int ldw,
    long long sA, long long sW, long long sC) {
    int bz = blockIdx.z;
    const bf16* A0b = A0 + (size_t)bz * sA;
    const bf16* Wb = W + (size_t)bz * sW;
    void* Cb = storef32 ? (void*)((float*)C + (size_t)bz * sC)
                        : (void*)((bf16*)C + (size_t)bz * sC);
    gemm128_core(A0b, A1, A2, Wb, bias, Cb, mul, mulmode, storef32, nchunks, ldw,
                 blockIdx.x, blockIdx.y);
}

// Fused q/k/v wrapper: z picks weights/bias/output/epilogue.
__global__ __launch_bounds__(256) void k_gemm_qkv(
    const bf16* __restrict__ A0, const bf16* __restrict__ A1, const bf16* __restrict__ A2,
    const bf16* __restrict__ Wq, const bf16* __restrict__ Wk, const bf16* __restrict__ Wv,
    const float* __restrict__ bq, const float* __restrict__ bk, const float* __restrict__ bv,
    bf16* __restrict__ Cq, bf16* __restrict__ Ck, bf16* __restrict__ Cv,
    const float* __restrict__ mulk, const float* __restrict__ mulv) {
    int z = blockIdx.z;
    const bf16* W = (z == 0) ? Wq : (z == 1 ? Wk : Wv);
    const float* bias = (z == 0) ? bq : (z == 1 ? bk : bv);
    bf16* C = (z == 0) ? Cq : (z == 1 ? Ck : Cv);
    const void* mul = (z == 0) ? nullptr : (z == 1 ? (const void*)mulk : (const void*)mulv);
    int mulmode = (z == 0) ? 0 : 2;
    gemm128_core(A0, A1, A2, W, bias, C, mul, mulmode, 0, 3, 3072,
                 blockIdx.x, blockIdx.y);
}

// ---------------------------------------------------------------------------
// v (B,N,D) -> vT (B,D,N)
// ---------------------------------------------------------------------------
__global__ void k_transpose(const bf16* __restrict__ v, bf16* __restrict__ vT) {
    __shared__ bf16 tile[32][33];
    int b = blockIdx.z;
    int n0 = blockIdx.x * 32, d0 = blockIdx.y * 32;
    int tx = threadIdx.x, ty = threadIdx.y; // (32,8)
    for (int i = 0; i < 32; i += 8)
        tile[ty + i][tx] = v[((size_t)b * NN + n0 + ty + i) * DD + d0 + tx];
    __syncthreads();
    for (int i = 0; i < 32; i += 8)
        vT[((size_t)b * DD + d0 + ty + i) * NN + n0 + tx] = tile[tx][ty + i];
}

// ---------------------------------------------------------------------------
// qa[m,e] = q[m,:] . wes[e,0:D]; kb[m,e] = k[m,:] . wes[e,D:2D]
// ---------------------------------------------------------------------------
__global__ __launch_bounds__(256) void k_qakb(const bf16* __restrict__ q, const bf16* __restrict__ k,
                                              const float* __restrict__ wes,
                                              float* __restrict__ qa, float* __restrict__ kb) {
    __shared__ float red[4];
    int m = blockIdx.x;
    int t = threadIdx.x;
    float pq[4] = {0.f, 0.f, 0.f, 0.f}, pk[4] = {0.f, 0.f, 0.f, 0.f};
    const bf16* qr = q + (size_t)m * DD;
    const bf16* kr = k + (size_t)m * DD;
    for (int d = t; d < DD; d += 256) {
        float qd = b2f(qr[d]);
        float kd = b2f(kr[d]);
#pragma unroll
        for (int e = 0; e < 4; ++e) {
            pq[e] += qd * wes[e * 2048 + d];
            pk[e] += kd * wes[e * 2048 + 1024 + d];
        }
    }
    for (int e = 0; e < 8; ++e) {
        float v = (e < 4) ? pq[e] : pk[e - 4];
        for (int o = 32; o > 0; o >>= 1) v += __shfl_down(v, o);
        if ((t & 63) == 0) red[t >> 6] = v;
        __syncthreads();
        if (t == 0) {
            float s = red[0] + red[1] + red[2] + red[3];
            (e < 4 ? qa : kb)[(size_t)m * 4 + (e & 3)] = s;
        }
        __syncthreads();
    }
}

// ---------------------------------------------------------------------------
// Edge scores + masked softmax: one block per (b,i) row.
// ---------------------------------------------------------------------------
__global__ __launch_bounds__(256) void k_attn(const int* __restrict__ adj, const float* __restrict__ qa,
                                              const float* __restrict__ kb, const int* __restrict__ typesPtr,
                                              bf16* __restrict__ prob) {
    __shared__ float lg[NN];
    __shared__ float red[4];
    __shared__ float red2[4];
    int m = blockIdx.x;
    int b = m >> 10;
    int t = threadIdx.x;
    int types = typesPtr[0];
    float qa4[4];
#pragma unroll
    for (int e = 0; e < 4; ++e) qa4[e] = qa[(size_t)m * 4 + e];
    const int* arow = adj + (size_t)m * NN;
    const float* kbb = kb + (size_t)(b << 10) * 4;

    float lmax = -3.0e38f;
    for (int j = t; j < NN; j += 256) {
        int a = arow[j];
        float l;
        if (a == 0) {
            l = -9.0e15f;
        } else if ((types >> a) & 1) {
            float s = qa4[a - 1] + kbb[(size_t)j * 4 + (a - 1)];
            l = s > 0.f ? s : 0.2f * s;
        } else {
            l = 0.f;
        }
        lg[j] = l;
        lmax = fmaxf(lmax, l);
    }
    for (int o = 32; o > 0; o >>= 1) lmax = fmaxf(lmax, __shfl_down(lmax, o));
    if ((t & 63) == 0) red[t >> 6] = lmax;
    __syncthreads();
    lmax = fmaxf(fmaxf(red[0], red[1]), fmaxf(red[2], red[3]));

    float lsum = 0.f;
    for (int j = t; j < NN; j += 256) {
        float ex = expf(lg[j] - lmax);
        lg[j] = ex;
        lsum += ex;
    }
    for (int o = 32; o > 0; o >>= 1) lsum += __shfl_down(lsum, o);
    if ((t & 63) == 0) red2[t >> 6] = lsum;
    __syncthreads();
    lsum = red2[0] + red2[1] + red2[2] + red2[3];
    float inv = 1.0f / lsum;

    bf16* prow = prob + (size_t)m * NN;
    for (int j = t; j < NN; j += 256) prow[j] = f2b(lg[j] * inv);
}

// ---------------------------------------------------------------------------
extern "C" void kernel_launch(void* const* d_in, const int* in_sizes, int n_in,
                              void* d_out, int out_size, void* d_ws, size_t ws_size,
                              hipStream_t stream) {
    const float* ents = (const float*)d_in[0];
    const float* mask = (const float*)d_in[1];
    const float* qenc = (const float*)d_in[2];
    const int* adj = (const int*)d_in[3];
    const int* types = (const int*)d_in[4];
    const float* initm = (const float*)d_in[5];
    const float* w_qin = (const float*)d_in[6];
    const float* b_qin = (const float*)d_in[7];
    const float* w_qt = (const float*)d_in[8];
    const float* b_qt = (const float*)d_in[9];
    const float* w_pl = (const float*)d_in[10];
    const float* b_pl = (const float*)d_in[11];
    const float* w_pc = (const float*)d_in[12];
    const float* b_pc = (const float*)d_in[13];
    const float* w_q = (const float*)d_in[14];
    const float* b_q = (const float*)d_in[15];
    const float* w_k = (const float*)d_in[16];
    const float* b_k = (const float*)d_in[17];
    const float* w_v = (const float*)d_in[18];
    const float* b_v = (const float*)d_in[19];
    const float* w_pk = (const float*)d_in[20];
    const float* b_pk = (const float*)d_in[21];
    const float* w_pv = (const float*)d_in[22];
    const float* b_pv = (const float*)d_in[23];
    const float* wes = (const float*)d_in[24];
    const float* w_mu = (const float*)d_in[25];
    const float* b_mu = (const float*)d_in[26];
    const float* w_cb = (const float*)d_in[27];
    const float* b_cb = (const float*)d_in[28];
    (void)in_sizes; (void)n_in; (void)out_size; (void)ws_size;

    char* p = (char*)d_ws;
    auto carve = [&](size_t bytes) {
        char* r = p;
        p += (bytes + 255) & ~(size_t)255;
        return r;
    };
    // fp32 smalls
    float* q_base = (float*)carve((size_t)NB * DD * 4);
    float* cmd = (float*)carve((size_t)NT_ITER * NB * DD * 4);
    float* pk = (float*)carve((size_t)NT_ITER * NB * DD * 4);
    float* pv = (float*)carve((size_t)NT_ITER * NB * DD * 4);
    float* qa = (float*)carve((size_t)MM * 4 * 4);
    float* kb = (float*)carve((size_t)MM * 4 * 4);
    // bf16 copies
    bf16* initm_bf = (bf16*)carve((size_t)DD * 2);
    bf16* ents_bf = (bf16*)carve((size_t)MM * DD * 2);
    bf16* wpl_bf = (bf16*)carve((size_t)DD * DD * 2);
    bf16* wpc_bf = (bf16*)carve((size_t)DD * DD * 2);
    bf16* wq_bf = (bf16*)carve((size_t)DD * 3 * DD * 2);
    bf16* wk_bf = (bf16*)carve((size_t)DD * 3 * DD * 2);
    bf16* wv_bf = (bf16*)carve((size_t)DD * 3 * DD * 2);
    bf16* wmu_bf = (bf16*)carve((size_t)DD * 2 * DD * 2);
    bf16* wcb_bf = (bf16*)carve((size_t)DD * 2 * DD * 2);
    // bf16 activations (aliasing dead buffers)
    bf16* x_ctx = (bf16*)carve((size_t)MM * DD * 2);
    bf16* xc = (bf16*)carve((size_t)MM * DD * 2);
    bf16* pl = (bf16*)carve((size_t)MM * DD * 2);
    bf16* plpc = (bf16*)carve((size_t)MM * DD * 2); // reused as vT after qkv
    bf16* qb = (bf16*)carve((size_t)MM * DD * 2);   // reused as msg after qakb
    bf16* kbuf = (bf16*)carve((size_t)MM * DD * 2);
    bf16* vbuf = (bf16*)carve((size_t)MM * DD * 2); // reused as prob after transpose
    bf16* vT = plpc;
    bf16* msg = qb;
    bf16* prob = vbuf;

    const dim3 blk(256);
    const dim3 gBig(32, 8, 1);   // M=4096 x N=1024, 128x128 tiles
    const dim3 gQkv(32, 8, 3);   // fused q/k/v
    const dim3 gMsg(8, 8, NB);   // per-batch M=1024

    // fp32 -> bf16 conversions (once per launch)
    k_f2b<<<1, blk, 0, stream>>>(initm, initm_bf, DD / 4);
    k_f2b<<<4096, blk, 0, stream>>>(ents, ents_bf, MM * DD / 4);
    k_f2b<<<1024, blk, 0, stream>>>(w_pl, wpl_bf, DD * DD / 4);
    k_f2b<<<1024, blk, 0, stream>>>(w_pc, wpc_bf, DD * DD / 4);
    k_f2b<<<3072, blk, 0, stream>>>(w_q, wq_bf, DD * 3 * DD / 4);
    k_f2b<<<3072, blk, 0, stream>>>(w_k, wk_bf, DD * 3 * DD / 4);
    k_f2b<<<3072, blk, 0, stream>>>(w_v, wv_bf, DD * 3 * DD / 4);
    k_f2b<<<2048, blk, 0, stream>>>(w_mu, wmu_bf, DD * 2 * DD / 4);
    k_f2b<<<2048, blk, 0, stream>>>(w_cb, wcb_bf, DD * 2 * DD / 4);

    k_qbase<<<1024, blk, 0, stream>>>(qenc, w_qin, b_qin, q_base);
    k_cmd<<<4096, blk, 0, stream>>>(q_base, w_qt, b_qt, cmd);
    k_pkpv<<<8192, blk, 0, stream>>>(cmd, w_pk, b_pk, w_pv, b_pv, pk, pv);
    k_init_xctx<<<2048, blk, 0, stream>>>(initm_bf, x_ctx);

    // pl = ents @ w_pl.T + b_pl  (loop-invariant)
    k_gemm_b<<<gBig, blk, 0, stream>>>(ents_bf, nullptr, nullptr, wpl_bf, b_pl, pl,
                                       nullptr, 0, 0, 1, 1024, 0, 0, 0);

    for (int t = 0; t < NT_ITER; ++t) {
        k_xc<<<2048, blk, 0, stream>>>(x_ctx, mask, xc);
        // plpc = (xc @ w_pc.T + b_pc) * pl
        k_gemm_b<<<gBig, blk, 0, stream>>>(xc, nullptr, nullptr, wpc_bf, b_pc, plpc,
                                           pl, 1, 0, 1, 1024, 0, 0, 0);
        // q,k,v fused: x_joint = [ents, xc, plpc]
        k_gemm_qkv<<<gQkv, blk, 0, stream>>>(ents_bf, xc, plpc,
                                             wq_bf, wk_bf, wv_bf,
                                             b_q, b_k, b_v,
                                             qb, kbuf, vbuf,
                                             pk + (size_t)t * NB * DD,
                                             pv + (size_t)t * NB * DD);
        k_qakb<<<4096, blk, 0, stream>>>(qb, kbuf, wes, qa, kb);
        k_transpose<<<dim3(32, 32, NB), dim3(32, 8), 0, stream>>>(vbuf, vT);
        k_attn<<<4096, blk, 0, stream>>>(adj, qa, kb, types, prob);
        // message[b] = prob[b] @ vT[b]^T
        k_gemm_b<<<gMsg, blk, 0, stream>>>(prob, nullptr, nullptr, vT, nullptr, msg,
                                           nullptr, 0, 0, 1, 1024,
                                           (long long)NN * NN, (long long)DD * NN, (long long)NN * DD);
        // x_ctx = [xc, msg] @ w_mu.T + b_mu
        k_gemm_b<<<gBig, blk, 0, stream>>>(xc, msg, nullptr, wmu_bf, b_mu, x_ctx,
                                           nullptr, 0, 0, 2, 2048, 0, 0, 0);
    }
    // out = [ents, x_ctx] @ w_cb.T + b_cb  (fp32 store)
    k_gemm_b<<<gBig, blk, 0, stream>>>(ents_bf, x_ctx, nullptr, wcb_bf, b_cb, (float*)d_out,
                                       nullptr, 0, 1, 2, 2048, 0, 0, 0);
}

// Round 4
// 1375.475 us; speedup vs baseline: 1.5672x; 1.0801x over previous
//
#include <hip/hip_runtime.h>
#include <hip/hip_bf16.h>
#include <stdint.h>
#include <stddef.h>

// QDGAT forward, MI355X gfx950.
// Round 4: (a) q/k GEMMs algebraically collapsed: qa/kb computed as
// x_joint @ (W^T @ wes-combination) -- removes 206 of 473 GFLOP;
// (b) all remaining GEMMs use 64x128 tiles (512-block grids, 2 blocks/CU)
// instead of 128x128 (256 blocks = 1/CU, measured 213 TF in round 3).
// Inputs/outputs fp32; GEMM operands bf16 (absmax budget 0.11, measured 0.031).

typedef __hip_bfloat16 bf16;
typedef __attribute__((ext_vector_type(8))) short short8;
typedef __attribute__((ext_vector_type(4))) float floatx4;

#define NB 4
#define NN 1024
#define DD 1024
#define NT_ITER 4
#define MM (NB * NN) // 4096

static __device__ __forceinline__ float b2f(bf16 x) { return __bfloat162float(x); }
static __device__ __forceinline__ bf16 f2b(float x) { return __float2bfloat16(x); }
static __device__ __forceinline__ unsigned short f2bu(float x) {
    bf16 h = __float2bfloat16(x);
    unsigned short u;
    __builtin_memcpy(&u, &h, 2);
    return u;
}
static __device__ __forceinline__ float bu2f(unsigned short u) {
    unsigned int t = (unsigned int)u << 16;
    float f;
    __builtin_memcpy(&f, &t, 4);
    return f;
}

// global -> LDS direct DMA, 16 B per lane. LDS dest = wave-uniform base + lane*16.
static __device__ __forceinline__ void gl_lds16(const void* g, void* l) {
    __builtin_amdgcn_global_load_lds(
        (const __attribute__((address_space(1))) unsigned int*)g,
        (__attribute__((address_space(3))) unsigned int*)l, 16, 0, 0);
}

// ---------------------------------------------------------------------------
// fp32 -> bf16 conversion, 4 elements/thread.
// ---------------------------------------------------------------------------
__global__ void k_f2b(const float* __restrict__ src, bf16* __restrict__ dst, int n4) {
    int i = blockIdx.x * 256 + threadIdx.x;
    if (i >= n4) return;
    float4 v = ((const float4*)src)[i];
    ushort4 o;
    o.x = f2bu(v.x); o.y = f2bu(v.y); o.z = f2bu(v.z); o.w = f2bu(v.w);
    ((ushort4*)dst)[i] = o;
}

// ---------------------------------------------------------------------------
// Wave-per-output GEMVs (coalesced weight-row reads, shuffle reduce).
// ---------------------------------------------------------------------------
__global__ __launch_bounds__(256) void k_qbase(const float* __restrict__ qenc, const float* __restrict__ w,
                                               const float* __restrict__ b, float* __restrict__ out) {
    int o = blockIdx.x * 4 + (threadIdx.x >> 6); // o = n*4 + r; 4096 outputs
    int lane = threadIdx.x & 63;
    int n = o >> 2, r = o & 3;
    const float* xr = qenc + (size_t)r * DD;
    const float* wr = w + (size_t)n * DD;
    float s = 0.f;
    for (int d = lane; d < DD; d += 64) s += xr[d] * wr[d];
    for (int off = 32; off; off >>= 1) s += __shfl_down(s, off);
    if (lane == 0) {
        s += b[n];
        out[(size_t)r * DD + n] = s > 0.f ? s : (expf(s) - 1.0f); // ELU
    }
}

__global__ __launch_bounds__(256) void k_cmd(const float* __restrict__ qb, const float* __restrict__ w_qt,
                                             const float* __restrict__ b_qt, float* __restrict__ cmd) {
    int o = blockIdx.x * 4 + (threadIdx.x >> 6); // o = t*4096 + n*4 + r; 16384
    int lane = threadIdx.x & 63;
    int r = o & 3, n = (o >> 2) & 1023, t = o >> 12;
    const float* xr = qb + (size_t)r * DD;
    const float* wr = w_qt + ((size_t)t * DD + n) * DD;
    float s = 0.f;
    for (int d = lane; d < DD; d += 64) s += xr[d] * wr[d];
    for (int off = 32; off; off >>= 1) s += __shfl_down(s, off);
    if (lane == 0) cmd[((size_t)t * NB + r) * DD + n] = s + b_qt[t * DD + n];
}

__global__ __launch_bounds__(256) void k_pkpv(const float* __restrict__ cmd,
                                              const float* __restrict__ w_pk, const float* __restrict__ b_pk,
                                              const float* __restrict__ w_pv, const float* __restrict__ b_pv,
                                              float* __restrict__ pk, float* __restrict__ pv) {
    int o = blockIdx.x * 4 + (threadIdx.x >> 6); // o = n*32 + half*16 + pair; 32768
    int lane = threadIdx.x & 63;
    int n = o >> 5, half = (o >> 4) & 1, pair = o & 15;
    const float* xr = cmd + (size_t)pair * DD;
    const float* wr = (half ? w_pv : w_pk) + (size_t)n * DD;
    float s = 0.f;
    for (int d = lane; d < DD; d += 64) s += xr[d] * wr[d];
    for (int off = 32; off; off >>= 1) s += __shfl_down(s, off);
    if (lane == 0)
        (half ? pv : pk)[(size_t)pair * DD + n] = s + (half ? b_pv : b_pk)[n];
}

// ---------------------------------------------------------------------------
// q/k collapse: combine kernels.
// wqtw[e,k3] = sum_d wes[e,d] * w_q[d,k3]           (loop-invariant)
// wkeff[t,b*4+e,k3] = sum_d w_k[d,k3]*pk[t,b,d]*wes[e,D+d]
// cq[e] = b_q . wes[e,:D];  ck[t*16+b*4+e] = sum_d b_k[d]*pk[t,b,d]*wes[e,D+d]
// ---------------------------------------------------------------------------
__global__ __launch_bounds__(256) void k_wqw(const float* __restrict__ w_q, const float* __restrict__ wes,
                                             float* __restrict__ wqtw) {
    __shared__ float swes[4][1024];
    int tid = threadIdx.x;
    for (int i = tid; i < 4096; i += 256)
        swes[i >> 10][i & 1023] = wes[(size_t)(i >> 10) * 2048 + (i & 1023)];
    __syncthreads();
    int k3 = blockIdx.x * 256 + tid;
    float a0 = 0.f, a1 = 0.f, a2 = 0.f, a3 = 0.f;
    for (int d = 0; d < 1024; ++d) {
        float wv = w_q[(size_t)d * 3072 + k3];
        a0 += wv * swes[0][d];
        a1 += wv * swes[1][d];
        a2 += wv * swes[2][d];
        a3 += wv * swes[3][d];
    }
    wqtw[0 * 3072 + k3] = a0;
    wqtw[1 * 3072 + k3] = a1;
    wqtw[2 * 3072 + k3] = a2;
    wqtw[3 * 3072 + k3] = a3;
}

__global__ __launch_bounds__(256) void k_wkv(const float* __restrict__ w_k, const float* __restrict__ wes,
                                             const float* __restrict__ pk, float* __restrict__ wkeff) {
    __shared__ float sc[16][1024]; // 64 KB
    int tid = threadIdx.x;
    int t = blockIdx.y;
    for (int i = tid; i < 16384; i += 256) {
        int be = i >> 10, d = i & 1023;
        int b = be >> 2, e = be & 3;
        sc[be][d] = pk[((size_t)t * NB + b) * DD + d] * wes[(size_t)e * 2048 + 1024 + d];
    }
    __syncthreads();
    int k3 = blockIdx.x * 256 + tid;
    float acc[16];
#pragma unroll
    for (int be = 0; be < 16; ++be) acc[be] = 0.f;
    for (int d = 0; d < 1024; ++d) {
        float wv = w_k[(size_t)d * 3072 + k3];
#pragma unroll
        for (int be = 0; be < 16; ++be) acc[be] += wv * sc[be][d];
    }
#pragma unroll
    for (int be = 0; be < 16; ++be)
        wkeff[((size_t)t * 16 + be) * 3072 + k3] = acc[be];
}

__global__ void k_consts(const float* __restrict__ b_q, const float* __restrict__ b_k,
                         const float* __restrict__ pk, const float* __restrict__ wes,
                         float* __restrict__ cq, float* __restrict__ ck) {
    int w = threadIdx.x >> 6, lane = threadIdx.x & 63;
    for (int o = w; o < 68; o += 4) {
        float s = 0.f;
        if (o < 4) {
            for (int d = lane; d < 1024; d += 64) s += b_q[d] * wes[(size_t)o * 2048 + d];
        } else {
            int oo = o - 4;
            int t = oo >> 4, b = (oo >> 2) & 3, e = oo & 3;
            for (int d = lane; d < 1024; d += 64)
                s += b_k[d] * pk[((size_t)t * NB + b) * DD + d] * wes[(size_t)e * 2048 + 1024 + d];
        }
        for (int off = 32; off; off >>= 1) s += __shfl_down(s, off);
        if (lane == 0) {
            if (o < 4) cq[o] = s;
            else ck[o - 4] = s;
        }
    }
}

// ---------------------------------------------------------------------------
// qa[m,e], kb[m,e] via collapsed projections: block per row m.
// ---------------------------------------------------------------------------
__global__ __launch_bounds__(256) void k_qakb2(const bf16* __restrict__ ents, const bf16* __restrict__ xc,
                                               const bf16* __restrict__ plpc,
                                               const float* __restrict__ wqtw, const float* __restrict__ wkeff_t,
                                               const float* __restrict__ cq, const float* __restrict__ ck_t,
                                               float* __restrict__ qa, float* __restrict__ kb) {
    __shared__ float red[4][8];
    int m = blockIdx.x;
    int b = m >> 10;
    int t = threadIdx.x;
    float aq[4] = {0.f, 0.f, 0.f, 0.f}, ak[4] = {0.f, 0.f, 0.f, 0.f};
    const bf16* rows[3] = {ents + (size_t)m * DD, xc + (size_t)m * DD, plpc + (size_t)m * DD};
#pragma unroll
    for (int c = 0; c < 3; ++c) {
        const bf16* row = rows[c];
        const float* wq = wqtw + c * 1024;
        const float* wk = wkeff_t + (size_t)b * 4 * 3072 + c * 1024;
        for (int d = t; d < 1024; d += 256) {
            float xv = b2f(row[d]);
#pragma unroll
            for (int e = 0; e < 4; ++e) {
                aq[e] += xv * wq[(size_t)e * 3072 + d];
                ak[e] += xv * wk[(size_t)e * 3072 + d];
            }
        }
    }
#pragma unroll
    for (int e = 0; e < 4; ++e) {
        float v = aq[e];
        for (int o = 32; o; o >>= 1) v += __shfl_down(v, o);
        if ((t & 63) == 0) red[t >> 6][e] = v;
        v = ak[e];
        for (int o = 32; o; o >>= 1) v += __shfl_down(v, o);
        if ((t & 63) == 0) red[t >> 6][e + 4] = v;
    }
    __syncthreads();
    if (t < 8) {
        float s = red[0][t] + red[1][t] + red[2][t] + red[3][t];
        if (t < 4) qa[(size_t)m * 4 + t] = s + cq[t];
        else kb[(size_t)m * 4 + (t - 4)] = s + ck_t[b * 4 + (t - 4)];
    }
}

// ---------------------------------------------------------------------------
// Elementwise (16 B / thread)
// ---------------------------------------------------------------------------
__global__ void k_init_xctx(const bf16* __restrict__ initm_bf, bf16* __restrict__ x_ctx) {
    int i = blockIdx.x * 256 + threadIdx.x;
    ((uint4*)x_ctx)[i] = ((const uint4*)initm_bf)[i & 127];
}

__global__ void k_xc(const bf16* __restrict__ x_ctx, const float* __restrict__ mask,
                     bf16* __restrict__ xc) {
    int i = blockIdx.x * 256 + threadIdx.x;
    float mk = mask[i >> 7];
    uint4 v = ((const uint4*)x_ctx)[i];
    unsigned short* u = (unsigned short*)&v;
#pragma unroll
    for (int j = 0; j < 8; ++j) u[j] = f2bu(bu2f(u[j]) * mk);
    ((uint4*)xc)[i] = v;
}

// ---------------------------------------------------------------------------
// 64x128-tile GEMM: C[m,n] = sum_c A_c[m,k]*W[n,c*1024+k] (+bias)(*mul)
// BK=64; 4 waves, each 32x64 (2x4 of 16x16x32 MFMA). LDS 24 KB.
// A_c lda=1024; W row-major ldw; C ldc=1024.
// mulmode: 0 none, 1 bf16 mul[m*1024+n], 2 f32 mul[(m>>10)*1024+n].
// ---------------------------------------------------------------------------
__device__ __forceinline__ void gemm64_core(
    const bf16* __restrict__ A0, const bf16* __restrict__ A1, const bf16* __restrict__ A2,
    const bf16* __restrict__ W, const float* __restrict__ bias, void* __restrict__ C,
    const void* __restrict__ mul, int mulmode, int storef32, int nchunks, int ldw,
    int bm, int bn) {
    __shared__ bf16 sAB[(64 + 128) * 64]; // A rows 0-63 at [0,4096), B rows 0-127 at [4096,12288)

    const int t = threadIdx.x;
    const int lane = t & 63;
    const int w = t >> 6;
    const int wm = (w & 1) * 32, wn = (w >> 1) * 64;
    const int srow = lane >> 3;      // 0..7
    const int scol = (lane & 7) * 8; // 0..56

    floatx4 acc[2][4];
#pragma unroll
    for (int i = 0; i < 2; ++i)
#pragma unroll
        for (int j = 0; j < 4; ++j) acc[i][j] = (floatx4){0.f, 0.f, 0.f, 0.f};

    const int lrow = lane & 15;
    const int kq = (lane >> 4) * 8;
    const int ktiles = nchunks * 16;

    for (int kt = 0; kt < ktiles; ++kt) {
        const int cidx = kt >> 4;
        const bf16* Ac = (cidx == 0) ? A0 : (cidx == 1 ? A1 : A2);
        const int klocal = (kt & 15) * 64;
        const int kglob = kt * 64;
        // 24 segments of 512 elems (8 rows x 64 cols); wave w stages segs w*6..w*6+5.
#pragma unroll
        for (int s = 0; s < 6; ++s) {
            int c = w * 6 + s;
            if (c < 8) { // A rows c*8..c*8+8
                const bf16* src = Ac + ((size_t)(bm * 64 + c * 8 + srow)) * 1024 + klocal + scol;
                gl_lds16(src, &sAB[c * 512]);
            } else { // B rows (c-8)*8..
                const bf16* src = W + ((size_t)(bn * 128 + (c - 8) * 8 + srow)) * (size_t)ldw + kglob + scol;
                gl_lds16(src, &sAB[c * 512]);
            }
        }
        __syncthreads();
#pragma unroll
        for (int ks = 0; ks < 2; ++ks) {
            const int ko = ks * 32 + kq;
            short8 af[2], bfr[4];
#pragma unroll
            for (int mi = 0; mi < 2; ++mi) af[mi] = *(const short8*)&sAB[(wm + mi * 16 + lrow) * 64 + ko];
#pragma unroll
            for (int ni = 0; ni < 4; ++ni) bfr[ni] = *(const short8*)&sAB[4096 + (wn + ni * 16 + lrow) * 64 + ko];
#pragma unroll
            for (int mi = 0; mi < 2; ++mi)
#pragma unroll
                for (int ni = 0; ni < 4; ++ni)
                    acc[mi][ni] = __builtin_amdgcn_mfma_f32_16x16x32_bf16(af[mi], bfr[ni], acc[mi][ni], 0, 0, 0);
        }
        __syncthreads();
    }

    const int qrow = (lane >> 4) * 4;
#pragma unroll
    for (int mi = 0; mi < 2; ++mi) {
#pragma unroll
        for (int ni = 0; ni < 4; ++ni) {
            int gn = bn * 128 + wn + ni * 16 + lrow;
            float bv = bias ? bias[gn] : 0.f;
#pragma unroll
            for (int r = 0; r < 4; ++r) {
                int gm = bm * 64 + wm + mi * 16 + qrow + r;
                float val = acc[mi][ni][r] + bv;
                if (mulmode == 1)
                    val *= b2f(((const bf16*)mul)[(size_t)gm * 1024 + gn]);
                else if (mulmode == 2)
                    val *= ((const float*)mul)[(size_t)(gm >> 10) * 1024 + gn];
                size_t ci = (size_t)gm * 1024 + gn;
                if (storef32)
                    ((float*)C)[ci] = val;
                else
                    ((bf16*)C)[ci] = f2b(val);
            }
        }
    }
}

__global__ __launch_bounds__(256) void k_gemm64(
    const bf16* __restrict__ A0, const bf16* __restrict__ A1, const bf16* __restrict__ A2,
    const bf16* __restrict__ W, const float* __restrict__ bias, void* __restrict__ C,
    const void* __restrict__ mul, int mulmode, int storef32, int nchunks, int ldw,
    long long sA, long long sW, long long sC) {
    int bz = blockIdx.z;
    const bf16* A0b = A0 + (size_t)bz * sA;
    const bf16* Wb = W + (size_t)bz * sW;
    void* Cb = storef32 ? (void*)((float*)C + (size_t)bz * sC)
                        : (void*)((bf16*)C + (size_t)bz * sC);
    gemm64_core(A0b, A1, A2, Wb, bias, Cb, mul, mulmode, storef32, nchunks, ldw,
                blockIdx.x, blockIdx.y);
}

// ---------------------------------------------------------------------------
// v (B,N,D) -> vT (B,D,N)
// ---------------------------------------------------------------------------
__global__ void k_transpose(const bf16* __restrict__ v, bf16* __restrict__ vT) {
    __shared__ bf16 tile[32][33];
    int b = blockIdx.z;
    int n0 = blockIdx.x * 32, d0 = blockIdx.y * 32;
    int tx = threadIdx.x, ty = threadIdx.y; // (32,8)
    for (int i = 0; i < 32; i += 8)
        tile[ty + i][tx] = v[((size_t)b * NN + n0 + ty + i) * DD + d0 + tx];
    __syncthreads();
    for (int i = 0; i < 32; i += 8)
        vT[((size_t)b * DD + d0 + ty + i) * NN + n0 + tx] = tile[tx][ty + i];
}

// ---------------------------------------------------------------------------
// Edge scores + masked softmax: one block per (b,i) row.
// ---------------------------------------------------------------------------
__global__ __launch_bounds__(256) void k_attn(const int* __restrict__ adj, const float* __restrict__ qa,
                                              const float* __restrict__ kb, const int* __restrict__ typesPtr,
                                              bf16* __restrict__ prob) {
    __shared__ float lg[NN];
    __shared__ float red[4];
    __shared__ float red2[4];
    int m = blockIdx.x;
    int b = m >> 10;
    int t = threadIdx.x;
    int types = typesPtr[0];
    float qa4[4];
#pragma unroll
    for (int e = 0; e < 4; ++e) qa4[e] = qa[(size_t)m * 4 + e];
    const int* arow = adj + (size_t)m * NN;
    const float* kbb = kb + (size_t)(b << 10) * 4;

    float lmax = -3.0e38f;
    for (int j = t; j < NN; j += 256) {
        int a = arow[j];
        float l;
        if (a == 0) {
            l = -9.0e15f;
        } else if ((types >> a) & 1) {
            float s = qa4[a - 1] + kbb[(size_t)j * 4 + (a - 1)];
            l = s > 0.f ? s : 0.2f * s;
        } else {
            l = 0.f;
        }
        lg[j] = l;
        lmax = fmaxf(lmax, l);
    }
    for (int o = 32; o > 0; o >>= 1) lmax = fmaxf(lmax, __shfl_down(lmax, o));
    if ((t & 63) == 0) red[t >> 6] = lmax;
    __syncthreads();
    lmax = fmaxf(fmaxf(red[0], red[1]), fmaxf(red[2], red[3]));

    float lsum = 0.f;
    for (int j = t; j < NN; j += 256) {
        float ex = expf(lg[j] - lmax);
        lg[j] = ex;
        lsum += ex;
    }
    for (int o = 32; o > 0; o >>= 1) lsum += __shfl_down(lsum, o);
    if ((t & 63) == 0) red2[t >> 6] = lsum;
    __syncthreads();
    lsum = red2[0] + red2[1] + red2[2] + red2[3];
    float inv = 1.0f / lsum;

    bf16* prow = prob + (size_t)m * NN;
    for (int j = t; j < NN; j += 256) prow[j] = f2b(lg[j] * inv);
}

// ---------------------------------------------------------------------------
extern "C" void kernel_launch(void* const* d_in, const int* in_sizes, int n_in,
                              void* d_out, int out_size, void* d_ws, size_t ws_size,
                              hipStream_t stream) {
    const float* ents = (const float*)d_in[0];
    const float* mask = (const float*)d_in[1];
    const float* qenc = (const float*)d_in[2];
    const int* adj = (const int*)d_in[3];
    const int* types = (const int*)d_in[4];
    const float* initm = (const float*)d_in[5];
    const float* w_qin = (const float*)d_in[6];
    const float* b_qin = (const float*)d_in[7];
    const float* w_qt = (const float*)d_in[8];
    const float* b_qt = (const float*)d_in[9];
    const float* w_pl = (const float*)d_in[10];
    const float* b_pl = (const float*)d_in[11];
    const float* w_pc = (const float*)d_in[12];
    const float* b_pc = (const float*)d_in[13];
    const float* w_q = (const float*)d_in[14];
    const float* b_q = (const float*)d_in[15];
    const float* w_k = (const float*)d_in[16];
    const float* b_k = (const float*)d_in[17];
    const float* w_v = (const float*)d_in[18];
    const float* b_v = (const float*)d_in[19];
    const float* w_pk = (const float*)d_in[20];
    const float* b_pk = (const float*)d_in[21];
    const float* w_pv = (const float*)d_in[22];
    const float* b_pv = (const float*)d_in[23];
    const float* wes = (const float*)d_in[24];
    const float* w_mu = (const float*)d_in[25];
    const float* b_mu = (const float*)d_in[26];
    const float* w_cb = (const float*)d_in[27];
    const float* b_cb = (const float*)d_in[28];
    (void)in_sizes; (void)n_in; (void)out_size; (void)ws_size;

    char* p = (char*)d_ws;
    auto carve = [&](size_t bytes) {
        char* r = p;
        p += (bytes + 255) & ~(size_t)255;
        return r;
    };
    // fp32 smalls
    float* q_base = (float*)carve((size_t)NB * DD * 4);
    float* cmd = (float*)carve((size_t)NT_ITER * NB * DD * 4);
    float* pk = (float*)carve((size_t)NT_ITER * NB * DD * 4);
    float* pv = (float*)carve((size_t)NT_ITER * NB * DD * 4);
    float* qa = (float*)carve((size_t)MM * 4 * 4);
    float* kb = (float*)carve((size_t)MM * 4 * 4);
    float* wqtw = (float*)carve((size_t)4 * 3072 * 4);
    float* wkeff = (float*)carve((size_t)NT_ITER * 16 * 3072 * 4);
    float* cq = (float*)carve(4 * 4);
    float* ck = (float*)carve(64 * 4);
    // bf16 copies
    bf16* initm_bf = (bf16*)carve((size_t)DD * 2);
    bf16* ents_bf = (bf16*)carve((size_t)MM * DD * 2);
    bf16* wpl_bf = (bf16*)carve((size_t)DD * DD * 2);
    bf16* wpc_bf = (bf16*)carve((size_t)DD * DD * 2);
    bf16* wv_bf = (bf16*)carve((size_t)DD * 3 * DD * 2);
    bf16* wmu_bf = (bf16*)carve((size_t)DD * 2 * DD * 2);
    bf16* wcb_bf = (bf16*)carve((size_t)DD * 2 * DD * 2);
    // bf16 activations
    bf16* x_ctx = (bf16*)carve((size_t)MM * DD * 2);
    bf16* xc = (bf16*)carve((size_t)MM * DD * 2);
    bf16* pl = (bf16*)carve((size_t)MM * DD * 2);
    bf16* plpc = (bf16*)carve((size_t)MM * DD * 2); // dead after k_qakb2 -> reused as vT
    bf16* vbuf = (bf16*)carve((size_t)MM * DD * 2);
    bf16* msg = (bf16*)carve((size_t)MM * DD * 2);
    bf16* prob = (bf16*)carve((size_t)NB * NN * NN * 2);
    bf16* vT = plpc;

    const dim3 blk(256);
    const dim3 g64(64, 8, 1);   // M=4096, N=1024, 64x128 tiles -> 512 blocks
    const dim3 gMsg(16, 8, NB); // per-batch M=1024 -> 512 blocks

    // fp32 -> bf16 conversions (once per launch)
    k_f2b<<<1, blk, 0, stream>>>(initm, initm_bf, DD / 4);
    k_f2b<<<4096, blk, 0, stream>>>(ents, ents_bf, MM * DD / 4);
    k_f2b<<<1024, blk, 0, stream>>>(w_pl, wpl_bf, DD * DD / 4);
    k_f2b<<<1024, blk, 0, stream>>>(w_pc, wpc_bf, DD * DD / 4);
    k_f2b<<<3072, blk, 0, stream>>>(w_v, wv_bf, DD * 3 * DD / 4);
    k_f2b<<<2048, blk, 0, stream>>>(w_mu, wmu_bf, DD * 2 * DD / 4);
    k_f2b<<<2048, blk, 0, stream>>>(w_cb, wcb_bf, DD * 2 * DD / 4);

    k_qbase<<<1024, blk, 0, stream>>>(qenc, w_qin, b_qin, q_base);
    k_cmd<<<4096, blk, 0, stream>>>(q_base, w_qt, b_qt, cmd);
    k_pkpv<<<8192, blk, 0, stream>>>(cmd, w_pk, b_pk, w_pv, b_pv, pk, pv);
    k_init_xctx<<<2048, blk, 0, stream>>>(initm_bf, x_ctx);

    // q/k collapse precompute (all t upfront)
    k_wqw<<<12, blk, 0, stream>>>(w_q, wes, wqtw);
    k_wkv<<<dim3(12, NT_ITER), blk, 0, stream>>>(w_k, wes, pk, wkeff);
    k_consts<<<1, blk, 0, stream>>>(b_q, b_k, pk, wes, cq, ck);

    // pl = ents @ w_pl.T + b_pl  (loop-invariant)
    k_gemm64<<<g64, blk, 0, stream>>>(ents_bf, nullptr, nullptr, wpl_bf, b_pl, pl,
                                      nullptr, 0, 0, 1, 1024, 0, 0, 0);

    for (int t = 0; t < NT_ITER; ++t) {
        k_xc<<<2048, blk, 0, stream>>>(x_ctx, mask, xc);
        // plpc = (xc @ w_pc.T + b_pc) * pl
        k_gemm64<<<g64, blk, 0, stream>>>(xc, nullptr, nullptr, wpc_bf, b_pc, plpc,
                                          pl, 1, 0, 1, 1024, 0, 0, 0);
        // v = (x_joint @ w_v.T + b_v) * pv[t,b,:]
        k_gemm64<<<g64, blk, 0, stream>>>(ents_bf, xc, plpc, wv_bf, b_v, vbuf,
                                          pv + (size_t)t * NB * DD, 2, 0, 3, 3072, 0, 0, 0);
        // qa/kb via collapsed projections (replaces q,k GEMMs + old qakb)
        k_qakb2<<<4096, blk, 0, stream>>>(ents_bf, xc, plpc,
                                          wqtw, wkeff + (size_t)t * 16 * 3072,
                                          cq, ck + t * 16, qa, kb);
        k_transpose<<<dim3(32, 32, NB), dim3(32, 8), 0, stream>>>(vbuf, vT);
        k_attn<<<4096, blk, 0, stream>>>(adj, qa, kb, types, prob);
        // message[b] = prob[b] @ v[b]  (NT with W = vT[b])
        k_gemm64<<<gMsg, blk, 0, stream>>>(prob, nullptr, nullptr, vT, nullptr, msg,
                                           nullptr, 0, 0, 1, 1024,
                                           (long long)NN * NN, (long long)DD * NN, (long long)NN * DD);
        // x_ctx = [xc, msg] @ w_mu.T + b_mu
        k_gemm64<<<g64, blk, 0, stream>>>(xc, msg, nullptr, wmu_bf, b_mu, x_ctx,
                                          nullptr, 0, 0, 2, 2048, 0, 0, 0);
    }
    // out = [ents, x_ctx] @ w_cb.T + b_cb  (fp32 store)
    k_gemm64<<<g64, blk, 0, stream>>>(ents_bf, x_ctx, nullptr, wcb_bf, b_cb, (float*)d_out,
                                      nullptr, 0, 1, 2, 2048, 0, 0, 0);
}

// Round 5
// 1212.289 us; speedup vs baseline: 1.7781x; 1.1346x over previous
//
#include <hip/hip_runtime.h>
#include <hip/hip_bf16.h>
#include <stdint.h>
#include <stddef.h>

// QDGAT forward, MI355X gfx950.
// Round 5: wqtw/wkeff precompute (round-4's 250us latency-bound scalar loops,
// 2% occupancy) recast as: fp32->bf16 weight transposes + two tiny MFMA GEMMs
// (M=64, N=3072, K=1024). Everything else unchanged from round 4.
// Inputs/outputs fp32; GEMM operands bf16 (absmax budget 0.11, measured 0.031).

typedef __hip_bfloat16 bf16;
typedef __attribute__((ext_vector_type(8))) short short8;
typedef __attribute__((ext_vector_type(4))) float floatx4;

#define NB 4
#define NN 1024
#define DD 1024
#define NT_ITER 4
#define MM (NB * NN) // 4096

static __device__ __forceinline__ float b2f(bf16 x) { return __bfloat162float(x); }
static __device__ __forceinline__ bf16 f2b(float x) { return __float2bfloat16(x); }
static __device__ __forceinline__ unsigned short f2bu(float x) {
    bf16 h = __float2bfloat16(x);
    unsigned short u;
    __builtin_memcpy(&u, &h, 2);
    return u;
}
static __device__ __forceinline__ float bu2f(unsigned short u) {
    unsigned int t = (unsigned int)u << 16;
    float f;
    __builtin_memcpy(&f, &t, 4);
    return f;
}

// global -> LDS direct DMA, 16 B per lane. LDS dest = wave-uniform base + lane*16.
static __device__ __forceinline__ void gl_lds16(const void* g, void* l) {
    __builtin_amdgcn_global_load_lds(
        (const __attribute__((address_space(1))) unsigned int*)g,
        (__attribute__((address_space(3))) unsigned int*)l, 16, 0, 0);
}

// ---------------------------------------------------------------------------
// fp32 -> bf16 conversion, 4 elements/thread.
// ---------------------------------------------------------------------------
__global__ void k_f2b(const float* __restrict__ src, bf16* __restrict__ dst, int n4) {
    int i = blockIdx.x * 256 + threadIdx.x;
    if (i >= n4) return;
    float4 v = ((const float4*)src)[i];
    ushort4 o;
    o.x = f2bu(v.x); o.y = f2bu(v.y); o.z = f2bu(v.z); o.w = f2bu(v.w);
    ((ushort4*)dst)[i] = o;
}

// ---------------------------------------------------------------------------
// fp32 (1024 x 3072) -> bf16 transposed (3072 x 1024).
// ---------------------------------------------------------------------------
__global__ void k_transw(const float* __restrict__ src, bf16* __restrict__ dst) {
    __shared__ float tile[32][33];
    int c0 = blockIdx.x * 32; // input col (0..3072)
    int r0 = blockIdx.y * 32; // input row (0..1024)
    int tx = threadIdx.x, ty = threadIdx.y; // (32,8)
    for (int i = 0; i < 32; i += 8)
        tile[ty + i][tx] = src[(size_t)(r0 + ty + i) * 3072 + c0 + tx];
    __syncthreads();
    for (int i = 0; i < 32; i += 8)
        dst[(size_t)(c0 + ty + i) * 1024 + r0 + tx] = f2b(tile[tx][ty + i]);
}

// ---------------------------------------------------------------------------
// Build A matrices for the wqtw / wkeff GEMMs (64 x 1024 bf16 each).
// Aq row e (e<4) = wes[e, :D]; rows 4..63 = 0.
// Ak row t*16+b*4+e = pk[t,b,:] * wes[e, D:2D].
// ---------------------------------------------------------------------------
__global__ void k_build_sc(const float* __restrict__ pk, const float* __restrict__ wes,
                           bf16* __restrict__ Aq, bf16* __restrict__ Ak) {
    int i = blockIdx.x * 256 + threadIdx.x; // 0..131071
    int half = i >> 16;
    int j = i & 65535;
    int row = j >> 10, d = j & 1023;
    if (half == 0) {
        Aq[j] = (row < 4) ? f2b(wes[(size_t)row * 2048 + d]) : f2b(0.f);
    } else {
        int t = row >> 4, b = (row >> 2) & 3, e = row & 3;
        Ak[j] = f2b(pk[((size_t)t * NB + b) * DD + d] * wes[(size_t)e * 2048 + 1024 + d]);
    }
}

// ---------------------------------------------------------------------------
// Wave-per-output GEMVs (coalesced weight-row reads, shuffle reduce).
// ---------------------------------------------------------------------------
__global__ __launch_bounds__(256) void k_qbase(const float* __restrict__ qenc, const float* __restrict__ w,
                                               const float* __restrict__ b, float* __restrict__ out) {
    int o = blockIdx.x * 4 + (threadIdx.x >> 6); // o = n*4 + r; 4096 outputs
    int lane = threadIdx.x & 63;
    int n = o >> 2, r = o & 3;
    const float* xr = qenc + (size_t)r * DD;
    const float* wr = w + (size_t)n * DD;
    float s = 0.f;
    for (int d = lane; d < DD; d += 64) s += xr[d] * wr[d];
    for (int off = 32; off; off >>= 1) s += __shfl_down(s, off);
    if (lane == 0) {
        s += b[n];
        out[(size_t)r * DD + n] = s > 0.f ? s : (expf(s) - 1.0f); // ELU
    }
}

__global__ __launch_bounds__(256) void k_cmd(const float* __restrict__ qb, const float* __restrict__ w_qt,
                                             const float* __restrict__ b_qt, float* __restrict__ cmd) {
    int o = blockIdx.x * 4 + (threadIdx.x >> 6); // o = t*4096 + n*4 + r; 16384
    int lane = threadIdx.x & 63;
    int r = o & 3, n = (o >> 2) & 1023, t = o >> 12;
    const float* xr = qb + (size_t)r * DD;
    const float* wr = w_qt + ((size_t)t * DD + n) * DD;
    float s = 0.f;
    for (int d = lane; d < DD; d += 64) s += xr[d] * wr[d];
    for (int off = 32; off; off >>= 1) s += __shfl_down(s, off);
    if (lane == 0) cmd[((size_t)t * NB + r) * DD + n] = s + b_qt[t * DD + n];
}

__global__ __launch_bounds__(256) void k_pkpv(const float* __restrict__ cmd,
                                              const float* __restrict__ w_pk, const float* __restrict__ b_pk,
                                              const float* __restrict__ w_pv, const float* __restrict__ b_pv,
                                              float* __restrict__ pk, float* __restrict__ pv) {
    int o = blockIdx.x * 4 + (threadIdx.x >> 6); // o = n*32 + half*16 + pair; 32768
    int lane = threadIdx.x & 63;
    int n = o >> 5, half = (o >> 4) & 1, pair = o & 15;
    const float* xr = cmd + (size_t)pair * DD;
    const float* wr = (half ? w_pv : w_pk) + (size_t)n * DD;
    float s = 0.f;
    for (int d = lane; d < DD; d += 64) s += xr[d] * wr[d];
    for (int off = 32; off; off >>= 1) s += __shfl_down(s, off);
    if (lane == 0)
        (half ? pv : pk)[(size_t)pair * DD + n] = s + (half ? b_pv : b_pk)[n];
}

__global__ void k_consts(const float* __restrict__ b_q, const float* __restrict__ b_k,
                         const float* __restrict__ pk, const float* __restrict__ wes,
                         float* __restrict__ cq, float* __restrict__ ck) {
    int w = threadIdx.x >> 6, lane = threadIdx.x & 63;
    for (int o = w; o < 68; o += 4) {
        float s = 0.f;
        if (o < 4) {
            for (int d = lane; d < 1024; d += 64) s += b_q[d] * wes[(size_t)o * 2048 + d];
        } else {
            int oo = o - 4;
            int t = oo >> 4, b = (oo >> 2) & 3, e = oo & 3;
            for (int d = lane; d < 1024; d += 64)
                s += b_k[d] * pk[((size_t)t * NB + b) * DD + d] * wes[(size_t)e * 2048 + 1024 + d];
        }
        for (int off = 32; off; off >>= 1) s += __shfl_down(s, off);
        if (lane == 0) {
            if (o < 4) cq[o] = s;
            else ck[o - 4] = s;
        }
    }
}

// ---------------------------------------------------------------------------
// qa[m,e], kb[m,e] via collapsed projections: block per row m.
// ---------------------------------------------------------------------------
__global__ __launch_bounds__(256) void k_qakb2(const bf16* __restrict__ ents, const bf16* __restrict__ xc,
                                               const bf16* __restrict__ plpc,
                                               const float* __restrict__ wqtw, const float* __restrict__ wkeff_t,
                                               const float* __restrict__ cq, const float* __restrict__ ck_t,
                                               float* __restrict__ qa, float* __restrict__ kb) {
    __shared__ float red[4][8];
    int m = blockIdx.x;
    int b = m >> 10;
    int t = threadIdx.x;
    float aq[4] = {0.f, 0.f, 0.f, 0.f}, ak[4] = {0.f, 0.f, 0.f, 0.f};
    const bf16* rows[3] = {ents + (size_t)m * DD, xc + (size_t)m * DD, plpc + (size_t)m * DD};
#pragma unroll
    for (int c = 0; c < 3; ++c) {
        const bf16* row = rows[c];
        const float* wq = wqtw + c * 1024;
        const float* wk = wkeff_t + (size_t)b * 4 * 3072 + c * 1024;
        for (int d = t; d < 1024; d += 256) {
            float xv = b2f(row[d]);
#pragma unroll
            for (int e = 0; e < 4; ++e) {
                aq[e] += xv * wq[(size_t)e * 3072 + d];
                ak[e] += xv * wk[(size_t)e * 3072 + d];
            }
        }
    }
#pragma unroll
    for (int e = 0; e < 4; ++e) {
        float v = aq[e];
        for (int o = 32; o; o >>= 1) v += __shfl_down(v, o);
        if ((t & 63) == 0) red[t >> 6][e] = v;
        v = ak[e];
        for (int o = 32; o; o >>= 1) v += __shfl_down(v, o);
        if ((t & 63) == 0) red[t >> 6][e + 4] = v;
    }
    __syncthreads();
    if (t < 8) {
        float s = red[0][t] + red[1][t] + red[2][t] + red[3][t];
        if (t < 4) qa[(size_t)m * 4 + t] = s + cq[t];
        else kb[(size_t)m * 4 + (t - 4)] = s + ck_t[b * 4 + (t - 4)];
    }
}

// ---------------------------------------------------------------------------
// Elementwise (16 B / thread)
// ---------------------------------------------------------------------------
__global__ void k_init_xctx(const bf16* __restrict__ initm_bf, bf16* __restrict__ x_ctx) {
    int i = blockIdx.x * 256 + threadIdx.x;
    ((uint4*)x_ctx)[i] = ((const uint4*)initm_bf)[i & 127];
}

__global__ void k_xc(const bf16* __restrict__ x_ctx, const float* __restrict__ mask,
                     bf16* __restrict__ xc) {
    int i = blockIdx.x * 256 + threadIdx.x;
    float mk = mask[i >> 7];
    uint4 v = ((const uint4*)x_ctx)[i];
    unsigned short* u = (unsigned short*)&v;
#pragma unroll
    for (int j = 0; j < 8; ++j) u[j] = f2bu(bu2f(u[j]) * mk);
    ((uint4*)xc)[i] = v;
}

// ---------------------------------------------------------------------------
// 64x128-tile GEMM: C[m,n] = sum_c A_c[m,k]*W[n,c*1024+k] (+bias)(*mul)
// BK=64; 4 waves, each 32x64 (2x4 of 16x16x32 MFMA). LDS 24 KB.
// A_c lda=1024; W row-major ldw; C row-major ldc.
// mulmode: 0 none, 1 bf16 mul[m*1024+n], 2 f32 mul[(m>>10)*1024+n].
// ---------------------------------------------------------------------------
__device__ __forceinline__ void gemm64_core(
    const bf16* __restrict__ A0, const bf16* __restrict__ A1, const bf16* __restrict__ A2,
    const bf16* __restrict__ W, const float* __restrict__ bias, void* __restrict__ C,
    const void* __restrict__ mul, int mulmode, int storef32, int nchunks, int ldw, int ldc,
    int bm, int bn) {
    __shared__ bf16 sAB[(64 + 128) * 64]; // A rows 0-63 at [0,4096), B rows 0-127 at [4096,12288)

    const int t = threadIdx.x;
    const int lane = t & 63;
    const int w = t >> 6;
    const int wm = (w & 1) * 32, wn = (w >> 1) * 64;
    const int srow = lane >> 3;      // 0..7
    const int scol = (lane & 7) * 8; // 0..56

    floatx4 acc[2][4];
#pragma unroll
    for (int i = 0; i < 2; ++i)
#pragma unroll
        for (int j = 0; j < 4; ++j) acc[i][j] = (floatx4){0.f, 0.f, 0.f, 0.f};

    const int lrow = lane & 15;
    const int kq = (lane >> 4) * 8;
    const int ktiles = nchunks * 16;

    for (int kt = 0; kt < ktiles; ++kt) {
        const int cidx = kt >> 4;
        const bf16* Ac = (cidx == 0) ? A0 : (cidx == 1 ? A1 : A2);
        const int klocal = (kt & 15) * 64;
        const int kglob = kt * 64;
        // 24 segments of 512 elems (8 rows x 64 cols); wave w stages segs w*6..w*6+5.
#pragma unroll
        for (int s = 0; s < 6; ++s) {
            int c = w * 6 + s;
            if (c < 8) { // A rows c*8..c*8+8
                const bf16* src = Ac + ((size_t)(bm * 64 + c * 8 + srow)) * 1024 + klocal + scol;
                gl_lds16(src, &sAB[c * 512]);
            } else { // B rows (c-8)*8..
                const bf16* src = W + ((size_t)(bn * 128 + (c - 8) * 8 + srow)) * (size_t)ldw + kglob + scol;
                gl_lds16(src, &sAB[c * 512]);
            }
        }
        __syncthreads();
#pragma unroll
        for (int ks = 0; ks < 2; ++ks) {
            const int ko = ks * 32 + kq;
            short8 af[2], bfr[4];
#pragma unroll
            for (int mi = 0; mi < 2; ++mi) af[mi] = *(const short8*)&sAB[(wm + mi * 16 + lrow) * 64 + ko];
#pragma unroll
            for (int ni = 0; ni < 4; ++ni) bfr[ni] = *(const short8*)&sAB[4096 + (wn + ni * 16 + lrow) * 64 + ko];
#pragma unroll
            for (int mi = 0; mi < 2; ++mi)
#pragma unroll
                for (int ni = 0; ni < 4; ++ni)
                    acc[mi][ni] = __builtin_amdgcn_mfma_f32_16x16x32_bf16(af[mi], bfr[ni], acc[mi][ni], 0, 0, 0);
        }
        __syncthreads();
    }

    const int qrow = (lane >> 4) * 4;
#pragma unroll
    for (int mi = 0; mi < 2; ++mi) {
#pragma unroll
        for (int ni = 0; ni < 4; ++ni) {
            int gn = bn * 128 + wn + ni * 16 + lrow;
            float bv = bias ? bias[gn] : 0.f;
#pragma unroll
            for (int r = 0; r < 4; ++r) {
                int gm = bm * 64 + wm + mi * 16 + qrow + r;
                float val = acc[mi][ni][r] + bv;
                if (mulmode == 1)
                    val *= b2f(((const bf16*)mul)[(size_t)gm * 1024 + gn]);
                else if (mulmode == 2)
                    val *= ((const float*)mul)[(size_t)(gm >> 10) * 1024 + gn];
                size_t ci = (size_t)gm * (size_t)ldc + gn;
                if (storef32)
                    ((float*)C)[ci] = val;
                else
                    ((bf16*)C)[ci] = f2b(val);
            }
        }
    }
}

__global__ __launch_bounds__(256) void k_gemm64(
    const bf16* __restrict__ A0, const bf16* __restrict__ A1, const bf16* __restrict__ A2,
    const bf16* __restrict__ W, const float* __restrict__ bias, void* __restrict__ C,
    const void* __restrict__ mul, int mulmode, int storef32, int nchunks, int ldw, int ldc,
    long long sA, long long sW, long long sC) {
    int bz = blockIdx.z;
    const bf16* A0b = A0 + (size_t)bz * sA;
    const bf16* Wb = W + (size_t)bz * sW;
    void* Cb = storef32 ? (void*)((float*)C + (size_t)bz * sC)
                        : (void*)((bf16*)C + (size_t)bz * sC);
    gemm64_core(A0b, A1, A2, Wb, bias, Cb, mul, mulmode, storef32, nchunks, ldw, ldc,
                blockIdx.x, blockIdx.y);
}

// ---------------------------------------------------------------------------
// v (B,N,D) -> vT (B,D,N)
// ---------------------------------------------------------------------------
__global__ void k_transpose(const bf16* __restrict__ v, bf16* __restrict__ vT) {
    __shared__ bf16 tile[32][33];
    int b = blockIdx.z;
    int n0 = blockIdx.x * 32, d0 = blockIdx.y * 32;
    int tx = threadIdx.x, ty = threadIdx.y; // (32,8)
    for (int i = 0; i < 32; i += 8)
        tile[ty + i][tx] = v[((size_t)b * NN + n0 + ty + i) * DD + d0 + tx];
    __syncthreads();
    for (int i = 0; i < 32; i += 8)
        vT[((size_t)b * DD + d0 + ty + i) * NN + n0 + tx] = tile[tx][ty + i];
}

// ---------------------------------------------------------------------------
// Edge scores + masked softmax: one block per (b,i) row.
// ---------------------------------------------------------------------------
__global__ __launch_bounds__(256) void k_attn(const int* __restrict__ adj, const float* __restrict__ qa,
                                              const float* __restrict__ kb, const int* __restrict__ typesPtr,
                                              bf16* __restrict__ prob) {
    __shared__ float lg[NN];
    __shared__ float red[4];
    __shared__ float red2[4];
    int m = blockIdx.x;
    int b = m >> 10;
    int t = threadIdx.x;
    int types = typesPtr[0];
    float qa4[4];
#pragma unroll
    for (int e = 0; e < 4; ++e) qa4[e] = qa[(size_t)m * 4 + e];
    const int* arow = adj + (size_t)m * NN;
    const float* kbb = kb + (size_t)(b << 10) * 4;

    float lmax = -3.0e38f;
    for (int j = t; j < NN; j += 256) {
        int a = arow[j];
        float l;
        if (a == 0) {
            l = -9.0e15f;
        } else if ((types >> a) & 1) {
            float s = qa4[a - 1] + kbb[(size_t)j * 4 + (a - 1)];
            l = s > 0.f ? s : 0.2f * s;
        } else {
            l = 0.f;
        }
        lg[j] = l;
        lmax = fmaxf(lmax, l);
    }
    for (int o = 32; o > 0; o >>= 1) lmax = fmaxf(lmax, __shfl_down(lmax, o));
    if ((t & 63) == 0) red[t >> 6] = lmax;
    __syncthreads();
    lmax = fmaxf(fmaxf(red[0], red[1]), fmaxf(red[2], red[3]));

    float lsum = 0.f;
    for (int j = t; j < NN; j += 256) {
        float ex = expf(lg[j] - lmax);
        lg[j] = ex;
        lsum += ex;
    }
    for (int o = 32; o > 0; o >>= 1) lsum += __shfl_down(lsum, o);
    if ((t & 63) == 0) red2[t >> 6] = lsum;
    __syncthreads();
    lsum = red2[0] + red2[1] + red2[2] + red2[3];
    float inv = 1.0f / lsum;

    bf16* prow = prob + (size_t)m * NN;
    for (int j = t; j < NN; j += 256) prow[j] = f2b(lg[j] * inv);
}

// ---------------------------------------------------------------------------
extern "C" void kernel_launch(void* const* d_in, const int* in_sizes, int n_in,
                              void* d_out, int out_size, void* d_ws, size_t ws_size,
                              hipStream_t stream) {
    const float* ents = (const float*)d_in[0];
    const float* mask = (const float*)d_in[1];
    const float* qenc = (const float*)d_in[2];
    const int* adj = (const int*)d_in[3];
    const int* types = (const int*)d_in[4];
    const float* initm = (const float*)d_in[5];
    const float* w_qin = (const float*)d_in[6];
    const float* b_qin = (const float*)d_in[7];
    const float* w_qt = (const float*)d_in[8];
    const float* b_qt = (const float*)d_in[9];
    const float* w_pl = (const float*)d_in[10];
    const float* b_pl = (const float*)d_in[11];
    const float* w_pc = (const float*)d_in[12];
    const float* b_pc = (const float*)d_in[13];
    const float* w_q = (const float*)d_in[14];
    const float* b_q = (const float*)d_in[15];
    const float* w_k = (const float*)d_in[16];
    const float* b_k = (const float*)d_in[17];
    const float* w_v = (const float*)d_in[18];
    const float* b_v = (const float*)d_in[19];
    const float* w_pk = (const float*)d_in[20];
    const float* b_pk = (const float*)d_in[21];
    const float* w_pv = (const float*)d_in[22];
    const float* b_pv = (const float*)d_in[23];
    const float* wes = (const float*)d_in[24];
    const float* w_mu = (const float*)d_in[25];
    const float* b_mu = (const float*)d_in[26];
    const float* w_cb = (const float*)d_in[27];
    const float* b_cb = (const float*)d_in[28];
    (void)in_sizes; (void)n_in; (void)out_size; (void)ws_size;

    char* p = (char*)d_ws;
    auto carve = [&](size_t bytes) {
        char* r = p;
        p += (bytes + 255) & ~(size_t)255;
        return r;
    };
    // fp32 smalls
    float* q_base = (float*)carve((size_t)NB * DD * 4);
    float* cmd = (float*)carve((size_t)NT_ITER * NB * DD * 4);
    float* pk = (float*)carve((size_t)NT_ITER * NB * DD * 4);
    float* pv = (float*)carve((size_t)NT_ITER * NB * DD * 4);
    float* qa = (float*)carve((size_t)MM * 4 * 4);
    float* kb = (float*)carve((size_t)MM * 4 * 4);
    float* wqtw = (float*)carve((size_t)64 * 3072 * 4);  // rows 0..3 used
    float* wkeff = (float*)carve((size_t)64 * 3072 * 4); // row t*16+b*4+e
    float* cq = (float*)carve(4 * 4);
    float* ck = (float*)carve(64 * 4);
    // bf16 copies
    bf16* initm_bf = (bf16*)carve((size_t)DD * 2);
    bf16* ents_bf = (bf16*)carve((size_t)MM * DD * 2);
    bf16* wpl_bf = (bf16*)carve((size_t)DD * DD * 2);
    bf16* wpc_bf = (bf16*)carve((size_t)DD * DD * 2);
    bf16* wv_bf = (bf16*)carve((size_t)DD * 3 * DD * 2);
    bf16* wmu_bf = (bf16*)carve((size_t)DD * 2 * DD * 2);
    bf16* wcb_bf = (bf16*)carve((size_t)DD * 2 * DD * 2);
    bf16* wqT_bf = (bf16*)carve((size_t)3 * DD * DD * 2); // w_q^T (3072 x 1024)
    bf16* wkT_bf = (bf16*)carve((size_t)3 * DD * DD * 2); // w_k^T
    bf16* Aq = (bf16*)carve((size_t)64 * DD * 2);
    bf16* Ak = (bf16*)carve((size_t)64 * DD * 2);
    // bf16 activations
    bf16* x_ctx = (bf16*)carve((size_t)MM * DD * 2);
    bf16* xc = (bf16*)carve((size_t)MM * DD * 2);
    bf16* pl = (bf16*)carve((size_t)MM * DD * 2);
    bf16* plpc = (bf16*)carve((size_t)MM * DD * 2); // dead after k_qakb2 -> reused as vT
    bf16* vbuf = (bf16*)carve((size_t)MM * DD * 2);
    bf16* msg = (bf16*)carve((size_t)MM * DD * 2);
    bf16* prob = (bf16*)carve((size_t)NB * NN * NN * 2);
    bf16* vT = plpc;

    const dim3 blk(256);
    const dim3 g64(64, 8, 1);   // M=4096, N=1024, 64x128 tiles -> 512 blocks
    const dim3 gMsg(16, 8, NB); // per-batch M=1024 -> 512 blocks
    const dim3 gPre(1, 24, 1);  // M=64, N=3072 precompute GEMMs

    // fp32 -> bf16 conversions (once per launch)
    k_f2b<<<1, blk, 0, stream>>>(initm, initm_bf, DD / 4);
    k_f2b<<<4096, blk, 0, stream>>>(ents, ents_bf, MM * DD / 4);
    k_f2b<<<1024, blk, 0, stream>>>(w_pl, wpl_bf, DD * DD / 4);
    k_f2b<<<1024, blk, 0, stream>>>(w_pc, wpc_bf, DD * DD / 4);
    k_f2b<<<3072, blk, 0, stream>>>(w_v, wv_bf, DD * 3 * DD / 4);
    k_f2b<<<2048, blk, 0, stream>>>(w_mu, wmu_bf, DD * 2 * DD / 4);
    k_f2b<<<2048, blk, 0, stream>>>(w_cb, wcb_bf, DD * 2 * DD / 4);
    k_transw<<<dim3(96, 32), dim3(32, 8), 0, stream>>>(w_q, wqT_bf);
    k_transw<<<dim3(96, 32), dim3(32, 8), 0, stream>>>(w_k, wkT_bf);

    k_qbase<<<1024, blk, 0, stream>>>(qenc, w_qin, b_qin, q_base);
    k_cmd<<<4096, blk, 0, stream>>>(q_base, w_qt, b_qt, cmd);
    k_pkpv<<<8192, blk, 0, stream>>>(cmd, w_pk, b_pk, w_pv, b_pv, pk, pv);
    k_init_xctx<<<2048, blk, 0, stream>>>(initm_bf, x_ctx);

    // q/k collapse precompute: A matrices, consts, then two tiny MFMA GEMMs.
    k_build_sc<<<512, blk, 0, stream>>>(pk, wes, Aq, Ak);
    k_consts<<<1, blk, 0, stream>>>(b_q, b_k, pk, wes, cq, ck);
    // wqtw(64x3072,f32) = Aq @ wqT^T ; wkeff = Ak @ wkT^T
    k_gemm64<<<gPre, blk, 0, stream>>>(Aq, nullptr, nullptr, wqT_bf, nullptr, wqtw,
                                       nullptr, 0, 1, 1, 1024, 3072, 0, 0, 0);
    k_gemm64<<<gPre, blk, 0, stream>>>(Ak, nullptr, nullptr, wkT_bf, nullptr, wkeff,
                                       nullptr, 0, 1, 1, 1024, 3072, 0, 0, 0);

    // pl = ents @ w_pl.T + b_pl  (loop-invariant)
    k_gemm64<<<g64, blk, 0, stream>>>(ents_bf, nullptr, nullptr, wpl_bf, b_pl, pl,
                                      nullptr, 0, 0, 1, 1024, 1024, 0, 0, 0);

    for (int t = 0; t < NT_ITER; ++t) {
        k_xc<<<2048, blk, 0, stream>>>(x_ctx, mask, xc);
        // plpc = (xc @ w_pc.T + b_pc) * pl
        k_gemm64<<<g64, blk, 0, stream>>>(xc, nullptr, nullptr, wpc_bf, b_pc, plpc,
                                          pl, 1, 0, 1, 1024, 1024, 0, 0, 0);
        // v = (x_joint @ w_v.T + b_v) * pv[t,b,:]
        k_gemm64<<<g64, blk, 0, stream>>>(ents_bf, xc, plpc, wv_bf, b_v, vbuf,
                                          pv + (size_t)t * NB * DD, 2, 0, 3, 3072, 1024, 0, 0, 0);
        // qa/kb via collapsed projections
        k_qakb2<<<4096, blk, 0, stream>>>(ents_bf, xc, plpc,
                                          wqtw, wkeff + (size_t)t * 16 * 3072,
                                          cq, ck + t * 16, qa, kb);
        k_transpose<<<dim3(32, 32, NB), dim3(32, 8), 0, stream>>>(vbuf, vT);
        k_attn<<<4096, blk, 0, stream>>>(adj, qa, kb, types, prob);
        // message[b] = prob[b] @ v[b]  (NT with W = vT[b])
        k_gemm64<<<gMsg, blk, 0, stream>>>(prob, nullptr, nullptr, vT, nullptr, msg,
                                           nullptr, 0, 0, 1, 1024, 1024,
                                           (long long)NN * NN, (long long)DD * NN, (long long)NN * DD);
        // x_ctx = [xc, msg] @ w_mu.T + b_mu
        k_gemm64<<<g64, blk, 0, stream>>>(xc, msg, nullptr, wmu_bf, b_mu, x_ctx,
                                          nullptr, 0, 0, 2, 2048, 1024, 0, 0, 0);
    }
    // out = [ents, x_ctx] @ w_cb.T + b_cb  (fp32 store)
    k_gemm64<<<g64, blk, 0, stream>>>(ents_bf, x_ctx, nullptr, wcb_bf, b_cb, (float*)d_out,
                                      nullptr, 0, 1, 2, 2048, 1024, 0, 0, 0);
}

// Round 6
// 1166.366 us; speedup vs baseline: 1.8481x; 1.0394x over previous
//
#include <hip/hip_runtime.h>
#include <hip/hip_bf16.h>
#include <stdint.h>
#include <stddef.h>

// QDGAT forward, MI355X gfx950.
// Round 6: (1) k_consts parallelized (was 1 block / 77us, round-5 top dispatch);
// (2) loop-invariant ents-chunk of the v GEMM hoisted: vent = ents @ Wv[:, :D]^T
// computed once (fp32), per-iter v GEMM is K=2048 + addC epilogue.
// Inputs/outputs fp32; GEMM operands bf16 (absmax budget 0.11, measured 0.031).

typedef __hip_bfloat16 bf16;
typedef __attribute__((ext_vector_type(8))) short short8;
typedef __attribute__((ext_vector_type(4))) float floatx4;

#define NB 4
#define NN 1024
#define DD 1024
#define NT_ITER 4
#define MM (NB * NN) // 4096

static __device__ __forceinline__ float b2f(bf16 x) { return __bfloat162float(x); }
static __device__ __forceinline__ bf16 f2b(float x) { return __float2bfloat16(x); }
static __device__ __forceinline__ unsigned short f2bu(float x) {
    bf16 h = __float2bfloat16(x);
    unsigned short u;
    __builtin_memcpy(&u, &h, 2);
    return u;
}
static __device__ __forceinline__ float bu2f(unsigned short u) {
    unsigned int t = (unsigned int)u << 16;
    float f;
    __builtin_memcpy(&f, &t, 4);
    return f;
}

// global -> LDS direct DMA, 16 B per lane. LDS dest = wave-uniform base + lane*16.
static __device__ __forceinline__ void gl_lds16(const void* g, void* l) {
    __builtin_amdgcn_global_load_lds(
        (const __attribute__((address_space(1))) unsigned int*)g,
        (__attribute__((address_space(3))) unsigned int*)l, 16, 0, 0);
}

// ---------------------------------------------------------------------------
// fp32 -> bf16 conversion, 4 elements/thread.
// ---------------------------------------------------------------------------
__global__ void k_f2b(const float* __restrict__ src, bf16* __restrict__ dst, int n4) {
    int i = blockIdx.x * 256 + threadIdx.x;
    if (i >= n4) return;
    float4 v = ((const float4*)src)[i];
    ushort4 o;
    o.x = f2bu(v.x); o.y = f2bu(v.y); o.z = f2bu(v.z); o.w = f2bu(v.w);
    ((ushort4*)dst)[i] = o;
}

// ---------------------------------------------------------------------------
// fp32 (1024 x 3072) -> bf16 transposed (3072 x 1024).
// ---------------------------------------------------------------------------
__global__ void k_transw(const float* __restrict__ src, bf16* __restrict__ dst) {
    __shared__ float tile[32][33];
    int c0 = blockIdx.x * 32; // input col (0..3072)
    int r0 = blockIdx.y * 32; // input row (0..1024)
    int tx = threadIdx.x, ty = threadIdx.y; // (32,8)
    for (int i = 0; i < 32; i += 8)
        tile[ty + i][tx] = src[(size_t)(r0 + ty + i) * 3072 + c0 + tx];
    __syncthreads();
    for (int i = 0; i < 32; i += 8)
        dst[(size_t)(c0 + ty + i) * 1024 + r0 + tx] = f2b(tile[tx][ty + i]);
}

// ---------------------------------------------------------------------------
// Build A matrices for the wqtw / wkeff GEMMs (64 x 1024 bf16 each).
// ---------------------------------------------------------------------------
__global__ void k_build_sc(const float* __restrict__ pk, const float* __restrict__ wes,
                           bf16* __restrict__ Aq, bf16* __restrict__ Ak) {
    int i = blockIdx.x * 256 + threadIdx.x; // 0..131071
    int half = i >> 16;
    int j = i & 65535;
    int row = j >> 10, d = j & 1023;
    if (half == 0) {
        Aq[j] = (row < 4) ? f2b(wes[(size_t)row * 2048 + d]) : f2b(0.f);
    } else {
        int t = row >> 4, b = (row >> 2) & 3, e = row & 3;
        Ak[j] = f2b(pk[((size_t)t * NB + b) * DD + d] * wes[(size_t)e * 2048 + 1024 + d]);
    }
}

// ---------------------------------------------------------------------------
// Wave-per-output GEMVs (coalesced weight-row reads, shuffle reduce).
// ---------------------------------------------------------------------------
__global__ __launch_bounds__(256) void k_qbase(const float* __restrict__ qenc, const float* __restrict__ w,
                                               const float* __restrict__ b, float* __restrict__ out) {
    int o = blockIdx.x * 4 + (threadIdx.x >> 6); // o = n*4 + r; 4096 outputs
    int lane = threadIdx.x & 63;
    int n = o >> 2, r = o & 3;
    const float* xr = qenc + (size_t)r * DD;
    const float* wr = w + (size_t)n * DD;
    float s = 0.f;
    for (int d = lane; d < DD; d += 64) s += xr[d] * wr[d];
    for (int off = 32; off; off >>= 1) s += __shfl_down(s, off);
    if (lane == 0) {
        s += b[n];
        out[(size_t)r * DD + n] = s > 0.f ? s : (expf(s) - 1.0f); // ELU
    }
}

__global__ __launch_bounds__(256) void k_cmd(const float* __restrict__ qb, const float* __restrict__ w_qt,
                                             const float* __restrict__ b_qt, float* __restrict__ cmd) {
    int o = blockIdx.x * 4 + (threadIdx.x >> 6); // o = t*4096 + n*4 + r; 16384
    int lane = threadIdx.x & 63;
    int r = o & 3, n = (o >> 2) & 1023, t = o >> 12;
    const float* xr = qb + (size_t)r * DD;
    const float* wr = w_qt + ((size_t)t * DD + n) * DD;
    float s = 0.f;
    for (int d = lane; d < DD; d += 64) s += xr[d] * wr[d];
    for (int off = 32; off; off >>= 1) s += __shfl_down(s, off);
    if (lane == 0) cmd[((size_t)t * NB + r) * DD + n] = s + b_qt[t * DD + n];
}

__global__ __launch_bounds__(256) void k_pkpv(const float* __restrict__ cmd,
                                              const float* __restrict__ w_pk, const float* __restrict__ b_pk,
                                              const float* __restrict__ w_pv, const float* __restrict__ b_pv,
                                              float* __restrict__ pk, float* __restrict__ pv) {
    int o = blockIdx.x * 4 + (threadIdx.x >> 6); // o = n*32 + half*16 + pair; 32768
    int lane = threadIdx.x & 63;
    int n = o >> 5, half = (o >> 4) & 1, pair = o & 15;
    const float* xr = cmd + (size_t)pair * DD;
    const float* wr = (half ? w_pv : w_pk) + (size_t)n * DD;
    float s = 0.f;
    for (int d = lane; d < DD; d += 64) s += xr[d] * wr[d];
    for (int off = 32; off; off >>= 1) s += __shfl_down(s, off);
    if (lane == 0)
        (half ? pv : pk)[(size_t)pair * DD + n] = s + (half ? b_pv : b_pk)[n];
}

// One wave per output (68 outputs): cq[0..3], ck[0..63].
__global__ void k_consts(const float* __restrict__ b_q, const float* __restrict__ b_k,
                         const float* __restrict__ pk, const float* __restrict__ wes,
                         float* __restrict__ cq, float* __restrict__ ck) {
    int o = blockIdx.x; // 0..67
    int lane = threadIdx.x;
    float s = 0.f;
    if (o < 4) {
        for (int d = lane; d < 1024; d += 64) s += b_q[d] * wes[(size_t)o * 2048 + d];
    } else {
        int oo = o - 4;
        int t = oo >> 4, b = (oo >> 2) & 3, e = oo & 3;
        for (int d = lane; d < 1024; d += 64)
            s += b_k[d] * pk[((size_t)t * NB + b) * DD + d] * wes[(size_t)e * 2048 + 1024 + d];
    }
    for (int off = 32; off; off >>= 1) s += __shfl_down(s, off);
    if (lane == 0) {
        if (o < 4) cq[o] = s;
        else ck[o - 4] = s;
    }
}

// ---------------------------------------------------------------------------
// qa[m,e], kb[m,e] via collapsed projections: block per row m.
// ---------------------------------------------------------------------------
__global__ __launch_bounds__(256) void k_qakb2(const bf16* __restrict__ ents, const bf16* __restrict__ xc,
                                               const bf16* __restrict__ plpc,
                                               const float* __restrict__ wqtw, const float* __restrict__ wkeff_t,
                                               const float* __restrict__ cq, const float* __restrict__ ck_t,
                                               float* __restrict__ qa, float* __restrict__ kb) {
    __shared__ float red[4][8];
    int m = blockIdx.x;
    int b = m >> 10;
    int t = threadIdx.x;
    float aq[4] = {0.f, 0.f, 0.f, 0.f}, ak[4] = {0.f, 0.f, 0.f, 0.f};
    const bf16* rows[3] = {ents + (size_t)m * DD, xc + (size_t)m * DD, plpc + (size_t)m * DD};
#pragma unroll
    for (int c = 0; c < 3; ++c) {
        const bf16* row = rows[c];
        const float* wq = wqtw + c * 1024;
        const float* wk = wkeff_t + (size_t)b * 4 * 3072 + c * 1024;
        for (int d = t; d < 1024; d += 256) {
            float xv = b2f(row[d]);
#pragma unroll
            for (int e = 0; e < 4; ++e) {
                aq[e] += xv * wq[(size_t)e * 3072 + d];
                ak[e] += xv * wk[(size_t)e * 3072 + d];
            }
        }
    }
#pragma unroll
    for (int e = 0; e < 4; ++e) {
        float v = aq[e];
        for (int o = 32; o; o >>= 1) v += __shfl_down(v, o);
        if ((t & 63) == 0) red[t >> 6][e] = v;
        v = ak[e];
        for (int o = 32; o; o >>= 1) v += __shfl_down(v, o);
        if ((t & 63) == 0) red[t >> 6][e + 4] = v;
    }
    __syncthreads();
    if (t < 8) {
        float s = red[0][t] + red[1][t] + red[2][t] + red[3][t];
        if (t < 4) qa[(size_t)m * 4 + t] = s + cq[t];
        else kb[(size_t)m * 4 + (t - 4)] = s + ck_t[b * 4 + (t - 4)];
    }
}

// ---------------------------------------------------------------------------
// Elementwise (16 B / thread)
// ---------------------------------------------------------------------------
__global__ void k_init_xctx(const bf16* __restrict__ initm_bf, bf16* __restrict__ x_ctx) {
    int i = blockIdx.x * 256 + threadIdx.x;
    ((uint4*)x_ctx)[i] = ((const uint4*)initm_bf)[i & 127];
}

__global__ void k_xc(const bf16* __restrict__ x_ctx, const float* __restrict__ mask,
                     bf16* __restrict__ xc) {
    int i = blockIdx.x * 256 + threadIdx.x;
    float mk = mask[i >> 7];
    uint4 v = ((const uint4*)x_ctx)[i];
    unsigned short* u = (unsigned short*)&v;
#pragma unroll
    for (int j = 0; j < 8; ++j) u[j] = f2bu(bu2f(u[j]) * mk);
    ((uint4*)xc)[i] = v;
}

// ---------------------------------------------------------------------------
// 64x128-tile GEMM: C[m,n] = sum_c A_c[m,k]*W[n,c*1024+k] (+bias)(+addC)(*mul)
// BK=64; 4 waves, each 32x64 (2x4 of 16x16x32 MFMA). LDS 24 KB.
// A_c lda=1024; W row-major ldw; C row-major ldc. addC fp32, same index as C.
// mulmode: 0 none, 1 bf16 mul[m*1024+n], 2 f32 mul[(m>>10)*1024+n].
// ---------------------------------------------------------------------------
__device__ __forceinline__ void gemm64_core(
    const bf16* __restrict__ A0, const bf16* __restrict__ A1, const bf16* __restrict__ A2,
    const bf16* __restrict__ W, const float* __restrict__ bias, void* __restrict__ C,
    const void* __restrict__ mul, const float* __restrict__ addC,
    int mulmode, int storef32, int nchunks, int ldw, int ldc,
    int bm, int bn) {
    __shared__ bf16 sAB[(64 + 128) * 64]; // A rows 0-63 at [0,4096), B rows 0-127 at [4096,12288)

    const int t = threadIdx.x;
    const int lane = t & 63;
    const int w = t >> 6;
    const int wm = (w & 1) * 32, wn = (w >> 1) * 64;
    const int srow = lane >> 3;      // 0..7
    const int scol = (lane & 7) * 8; // 0..56

    floatx4 acc[2][4];
#pragma unroll
    for (int i = 0; i < 2; ++i)
#pragma unroll
        for (int j = 0; j < 4; ++j) acc[i][j] = (floatx4){0.f, 0.f, 0.f, 0.f};

    const int lrow = lane & 15;
    const int kq = (lane >> 4) * 8;
    const int ktiles = nchunks * 16;

    for (int kt = 0; kt < ktiles; ++kt) {
        const int cidx = kt >> 4;
        const bf16* Ac = (cidx == 0) ? A0 : (cidx == 1 ? A1 : A2);
        const int klocal = (kt & 15) * 64;
        const int kglob = kt * 64;
        // 24 segments of 512 elems (8 rows x 64 cols); wave w stages segs w*6..w*6+5.
#pragma unroll
        for (int s = 0; s < 6; ++s) {
            int c = w * 6 + s;
            if (c < 8) { // A rows c*8..c*8+8
                const bf16* src = Ac + ((size_t)(bm * 64 + c * 8 + srow)) * 1024 + klocal + scol;
                gl_lds16(src, &sAB[c * 512]);
            } else { // B rows (c-8)*8..
                const bf16* src = W + ((size_t)(bn * 128 + (c - 8) * 8 + srow)) * (size_t)ldw + kglob + scol;
                gl_lds16(src, &sAB[c * 512]);
            }
        }
        __syncthreads();
#pragma unroll
        for (int ks = 0; ks < 2; ++ks) {
            const int ko = ks * 32 + kq;
            short8 af[2], bfr[4];
#pragma unroll
            for (int mi = 0; mi < 2; ++mi) af[mi] = *(const short8*)&sAB[(wm + mi * 16 + lrow) * 64 + ko];
#pragma unroll
            for (int ni = 0; ni < 4; ++ni) bfr[ni] = *(const short8*)&sAB[4096 + (wn + ni * 16 + lrow) * 64 + ko];
#pragma unroll
            for (int mi = 0; mi < 2; ++mi)
#pragma unroll
                for (int ni = 0; ni < 4; ++ni)
                    acc[mi][ni] = __builtin_amdgcn_mfma_f32_16x16x32_bf16(af[mi], bfr[ni], acc[mi][ni], 0, 0, 0);
        }
        __syncthreads();
    }

    const int qrow = (lane >> 4) * 4;
#pragma unroll
    for (int mi = 0; mi < 2; ++mi) {
#pragma unroll
        for (int ni = 0; ni < 4; ++ni) {
            int gn = bn * 128 + wn + ni * 16 + lrow;
            float bv = bias ? bias[gn] : 0.f;
#pragma unroll
            for (int r = 0; r < 4; ++r) {
                int gm = bm * 64 + wm + mi * 16 + qrow + r;
                size_t ci = (size_t)gm * (size_t)ldc + gn;
                float val = acc[mi][ni][r] + bv;
                if (addC) val += addC[ci];
                if (mulmode == 1)
                    val *= b2f(((const bf16*)mul)[(size_t)gm * 1024 + gn]);
                else if (mulmode == 2)
                    val *= ((const float*)mul)[(size_t)(gm >> 10) * 1024 + gn];
                if (storef32)
                    ((float*)C)[ci] = val;
                else
                    ((bf16*)C)[ci] = f2b(val);
            }
        }
    }
}

__global__ __launch_bounds__(256) void k_gemm64(
    const bf16* __restrict__ A0, const bf16* __restrict__ A1, const bf16* __restrict__ A2,
    const bf16* __restrict__ W, const float* __restrict__ bias, void* __restrict__ C,
    const void* __restrict__ mul, const float* __restrict__ addC,
    int mulmode, int storef32, int nchunks, int ldw, int ldc,
    long long sA, long long sW, long long sC) {
    int bz = blockIdx.z;
    const bf16* A0b = A0 + (size_t)bz * sA;
    const bf16* Wb = W + (size_t)bz * sW;
    void* Cb = storef32 ? (void*)((float*)C + (size_t)bz * sC)
                        : (void*)((bf16*)C + (size_t)bz * sC);
    gemm64_core(A0b, A1, A2, Wb, bias, Cb, mul, addC, mulmode, storef32, nchunks, ldw, ldc,
                blockIdx.x, blockIdx.y);
}

// ---------------------------------------------------------------------------
// v (B,N,D) -> vT (B,D,N)
// ---------------------------------------------------------------------------
__global__ void k_transpose(const bf16* __restrict__ v, bf16* __restrict__ vT) {
    __shared__ bf16 tile[32][33];
    int b = blockIdx.z;
    int n0 = blockIdx.x * 32, d0 = blockIdx.y * 32;
    int tx = threadIdx.x, ty = threadIdx.y; // (32,8)
    for (int i = 0; i < 32; i += 8)
        tile[ty + i][tx] = v[((size_t)b * NN + n0 + ty + i) * DD + d0 + tx];
    __syncthreads();
    for (int i = 0; i < 32; i += 8)
        vT[((size_t)b * DD + d0 + ty + i) * NN + n0 + tx] = tile[tx][ty + i];
}

// ---------------------------------------------------------------------------
// Edge scores + masked softmax: one block per (b,i) row.
// ---------------------------------------------------------------------------
__global__ __launch_bounds__(256) void k_attn(const int* __restrict__ adj, const float* __restrict__ qa,
                                              const float* __restrict__ kb, const int* __restrict__ typesPtr,
                                              bf16* __restrict__ prob) {
    __shared__ float lg[NN];
    __shared__ float red[4];
    __shared__ float red2[4];
    int m = blockIdx.x;
    int b = m >> 10;
    int t = threadIdx.x;
    int types = typesPtr[0];
    float qa4[4];
#pragma unroll
    for (int e = 0; e < 4; ++e) qa4[e] = qa[(size_t)m * 4 + e];
    const int* arow = adj + (size_t)m * NN;
    const float* kbb = kb + (size_t)(b << 10) * 4;

    float lmax = -3.0e38f;
    for (int j = t; j < NN; j += 256) {
        int a = arow[j];
        float l;
        if (a == 0) {
            l = -9.0e15f;
        } else if ((types >> a) & 1) {
            float s = qa4[a - 1] + kbb[(size_t)j * 4 + (a - 1)];
            l = s > 0.f ? s : 0.2f * s;
        } else {
            l = 0.f;
        }
        lg[j] = l;
        lmax = fmaxf(lmax, l);
    }
    for (int o = 32; o > 0; o >>= 1) lmax = fmaxf(lmax, __shfl_down(lmax, o));
    if ((t & 63) == 0) red[t >> 6] = lmax;
    __syncthreads();
    lmax = fmaxf(fmaxf(red[0], red[1]), fmaxf(red[2], red[3]));

    float lsum = 0.f;
    for (int j = t; j < NN; j += 256) {
        float ex = expf(lg[j] - lmax);
        lg[j] = ex;
        lsum += ex;
    }
    for (int o = 32; o > 0; o >>= 1) lsum += __shfl_down(lsum, o);
    if ((t & 63) == 0) red2[t >> 6] = lsum;
    __syncthreads();
    lsum = red2[0] + red2[1] + red2[2] + red2[3];
    float inv = 1.0f / lsum;

    bf16* prow = prob + (size_t)m * NN;
    for (int j = t; j < NN; j += 256) prow[j] = f2b(lg[j] * inv);
}

// ---------------------------------------------------------------------------
extern "C" void kernel_launch(void* const* d_in, const int* in_sizes, int n_in,
                              void* d_out, int out_size, void* d_ws, size_t ws_size,
                              hipStream_t stream) {
    const float* ents = (const float*)d_in[0];
    const float* mask = (const float*)d_in[1];
    const float* qenc = (const float*)d_in[2];
    const int* adj = (const int*)d_in[3];
    const int* types = (const int*)d_in[4];
    const float* initm = (const float*)d_in[5];
    const float* w_qin = (const float*)d_in[6];
    const float* b_qin = (const float*)d_in[7];
    const float* w_qt = (const float*)d_in[8];
    const float* b_qt = (const float*)d_in[9];
    const float* w_pl = (const float*)d_in[10];
    const float* b_pl = (const float*)d_in[11];
    const float* w_pc = (const float*)d_in[12];
    const float* b_pc = (const float*)d_in[13];
    const float* w_q = (const float*)d_in[14];
    const float* b_q = (const float*)d_in[15];
    const float* w_k = (const float*)d_in[16];
    const float* b_k = (const float*)d_in[17];
    const float* w_v = (const float*)d_in[18];
    const float* b_v = (const float*)d_in[19];
    const float* w_pk = (const float*)d_in[20];
    const float* b_pk = (const float*)d_in[21];
    const float* w_pv = (const float*)d_in[22];
    const float* b_pv = (const float*)d_in[23];
    const float* wes = (const float*)d_in[24];
    const float* w_mu = (const float*)d_in[25];
    const float* b_mu = (const float*)d_in[26];
    const float* w_cb = (const float*)d_in[27];
    const float* b_cb = (const float*)d_in[28];
    (void)in_sizes; (void)n_in; (void)out_size; (void)ws_size;

    char* p = (char*)d_ws;
    auto carve = [&](size_t bytes) {
        char* r = p;
        p += (bytes + 255) & ~(size_t)255;
        return r;
    };
    // fp32 smalls
    float* q_base = (float*)carve((size_t)NB * DD * 4);
    float* cmd = (float*)carve((size_t)NT_ITER * NB * DD * 4);
    float* pk = (float*)carve((size_t)NT_ITER * NB * DD * 4);
    float* pv = (float*)carve((size_t)NT_ITER * NB * DD * 4);
    float* qa = (float*)carve((size_t)MM * 4 * 4);
    float* kb = (float*)carve((size_t)MM * 4 * 4);
    float* wqtw = (float*)carve((size_t)64 * 3072 * 4);  // rows 0..3 used
    float* wkeff = (float*)carve((size_t)64 * 3072 * 4); // row t*16+b*4+e
    float* cq = (float*)carve(4 * 4);
    float* ck = (float*)carve(64 * 4);
    float* vent = (float*)carve((size_t)MM * DD * 4); // ents @ Wv[:, :D]^T (fp32)
    // bf16 copies
    bf16* initm_bf = (bf16*)carve((size_t)DD * 2);
    bf16* ents_bf = (bf16*)carve((size_t)MM * DD * 2);
    bf16* wpl_bf = (bf16*)carve((size_t)DD * DD * 2);
    bf16* wpc_bf = (bf16*)carve((size_t)DD * DD * 2);
    bf16* wv_bf = (bf16*)carve((size_t)DD * 3 * DD * 2);
    bf16* wmu_bf = (bf16*)carve((size_t)DD * 2 * DD * 2);
    bf16* wcb_bf = (bf16*)carve((size_t)DD * 2 * DD * 2);
    bf16* wqT_bf = (bf16*)carve((size_t)3 * DD * DD * 2); // w_q^T (3072 x 1024)
    bf16* wkT_bf = (bf16*)carve((size_t)3 * DD * DD * 2); // w_k^T
    bf16* Aq = (bf16*)carve((size_t)64 * DD * 2);
    bf16* Ak = (bf16*)carve((size_t)64 * DD * 2);
    // bf16 activations
    bf16* x_ctx = (bf16*)carve((size_t)MM * DD * 2);
    bf16* xc = (bf16*)carve((size_t)MM * DD * 2);
    bf16* pl = (bf16*)carve((size_t)MM * DD * 2);
    bf16* plpc = (bf16*)carve((size_t)MM * DD * 2); // dead after k_qakb2 -> reused as vT
    bf16* vbuf = (bf16*)carve((size_t)MM * DD * 2);
    bf16* msg = (bf16*)carve((size_t)MM * DD * 2);
    bf16* prob = (bf16*)carve((size_t)NB * NN * NN * 2);
    bf16* vT = plpc;

    const dim3 blk(256);
    const dim3 g64(64, 8, 1);   // M=4096, N=1024, 64x128 tiles -> 512 blocks
    const dim3 gMsg(16, 8, NB); // per-batch M=1024 -> 512 blocks
    const dim3 gPre(1, 24, 1);  // M=64, N=3072 precompute GEMMs

    // fp32 -> bf16 conversions (once per launch)
    k_f2b<<<1, blk, 0, stream>>>(initm, initm_bf, DD / 4);
    k_f2b<<<4096, blk, 0, stream>>>(ents, ents_bf, MM * DD / 4);
    k_f2b<<<1024, blk, 0, stream>>>(w_pl, wpl_bf, DD * DD / 4);
    k_f2b<<<1024, blk, 0, stream>>>(w_pc, wpc_bf, DD * DD / 4);
    k_f2b<<<3072, blk, 0, stream>>>(w_v, wv_bf, DD * 3 * DD / 4);
    k_f2b<<<2048, blk, 0, stream>>>(w_mu, wmu_bf, DD * 2 * DD / 4);
    k_f2b<<<2048, blk, 0, stream>>>(w_cb, wcb_bf, DD * 2 * DD / 4);
    k_transw<<<dim3(96, 32), dim3(32, 8), 0, stream>>>(w_q, wqT_bf);
    k_transw<<<dim3(96, 32), dim3(32, 8), 0, stream>>>(w_k, wkT_bf);

    k_qbase<<<1024, blk, 0, stream>>>(qenc, w_qin, b_qin, q_base);
    k_cmd<<<4096, blk, 0, stream>>>(q_base, w_qt, b_qt, cmd);
    k_pkpv<<<8192, blk, 0, stream>>>(cmd, w_pk, b_pk, w_pv, b_pv, pk, pv);
    k_init_xctx<<<2048, blk, 0, stream>>>(initm_bf, x_ctx);

    // q/k collapse precompute: A matrices, consts, then two tiny MFMA GEMMs.
    k_build_sc<<<512, blk, 0, stream>>>(pk, wes, Aq, Ak);
    k_consts<<<68, 64, 0, stream>>>(b_q, b_k, pk, wes, cq, ck);
    // wqtw(64x3072,f32) = Aq @ wqT^T ; wkeff = Ak @ wkT^T
    k_gemm64<<<gPre, blk, 0, stream>>>(Aq, nullptr, nullptr, wqT_bf, nullptr, wqtw,
                                       nullptr, nullptr, 0, 1, 1, 1024, 3072, 0, 0, 0);
    k_gemm64<<<gPre, blk, 0, stream>>>(Ak, nullptr, nullptr, wkT_bf, nullptr, wkeff,
                                       nullptr, nullptr, 0, 1, 1, 1024, 3072, 0, 0, 0);

    // Loop-invariant GEMMs:
    // pl = ents @ w_pl.T + b_pl
    k_gemm64<<<g64, blk, 0, stream>>>(ents_bf, nullptr, nullptr, wpl_bf, b_pl, pl,
                                      nullptr, nullptr, 0, 0, 1, 1024, 1024, 0, 0, 0);
    // vent = ents @ w_v[:, :D].T  (fp32, no bias/mul)
    k_gemm64<<<g64, blk, 0, stream>>>(ents_bf, nullptr, nullptr, wv_bf, nullptr, vent,
                                      nullptr, nullptr, 0, 1, 1, 3072, 1024, 0, 0, 0);

    for (int t = 0; t < NT_ITER; ++t) {
        k_xc<<<2048, blk, 0, stream>>>(x_ctx, mask, xc);
        // plpc = (xc @ w_pc.T + b_pc) * pl
        k_gemm64<<<g64, blk, 0, stream>>>(xc, nullptr, nullptr, wpc_bf, b_pc, plpc,
                                          pl, nullptr, 1, 0, 1, 1024, 1024, 0, 0, 0);
        // v = (vent + [xc, plpc] @ w_v[:, D:].T + b_v) * pv[t,b,:]
        k_gemm64<<<g64, blk, 0, stream>>>(xc, plpc, nullptr, wv_bf + 1024, b_v, vbuf,
                                          pv + (size_t)t * NB * DD, vent, 2, 0, 2, 3072, 1024, 0, 0, 0);
        // qa/kb via collapsed projections
        k_qakb2<<<4096, blk, 0, stream>>>(ents_bf, xc, plpc,
                                          wqtw, wkeff + (size_t)t * 16 * 3072,
                                          cq, ck + t * 16, qa, kb);
        k_transpose<<<dim3(32, 32, NB), dim3(32, 8), 0, stream>>>(vbuf, vT);
        k_attn<<<4096, blk, 0, stream>>>(adj, qa, kb, types, prob);
        // message[b] = prob[b] @ v[b]  (NT with W = vT[b])
        k_gemm64<<<gMsg, blk, 0, stream>>>(prob, nullptr, nullptr, vT, nullptr, msg,
                                           nullptr, nullptr, 0, 0, 1, 1024, 1024,
                                           (long long)NN * NN, (long long)DD * NN, (long long)NN * DD);
        // x_ctx = [xc, msg] @ w_mu.T + b_mu
        k_gemm64<<<g64, blk, 0, stream>>>(xc, msg, nullptr, wmu_bf, b_mu, x_ctx,
                                          nullptr, nullptr, 0, 0, 2, 2048, 1024, 0, 0, 0);
    }
    // out = [ents, x_ctx] @ w_cb.T + b_cb  (fp32 store)
    k_gemm64<<<g64, blk, 0, stream>>>(ents_bf, x_ctx, nullptr, wcb_bf, b_cb, (float*)d_out,
                                      nullptr, nullptr, 0, 1, 2, 2048, 1024, 0, 0, 0);
}

// Round 7
// 1105.710 us; speedup vs baseline: 1.9495x; 1.0549x over previous
//
#include <hip/hip_runtime.h>
#include <hip/hip_bf16.h>
#include <stdint.h>
#include <stddef.h>

// QDGAT forward, MI355X gfx950.
// Round 7: (1) GEMM tiles 64x128 -> 64x64: grids go 512 -> 1024 blocks
// (2 -> 4 blocks/CU). Round-6 counters showed latency-bound GEMMs (MfmaUtil
// 11%, HBM 10%, staging 7.3 TB/s << 34.5 L2 ceiling) with occupancy capped by
// grid size, not resources. (2) k_xc fused into the mu-GEMM epilogue
// (mulmode=3 dual-store) and the init kernel.
// Inputs/outputs fp32; GEMM operands bf16 (absmax budget 0.11, measured 0.031).

typedef __hip_bfloat16 bf16;
typedef __attribute__((ext_vector_type(8))) short short8;
typedef __attribute__((ext_vector_type(4))) float floatx4;

#define NB 4
#define NN 1024
#define DD 1024
#define NT_ITER 4
#define MM (NB * NN) // 4096

static __device__ __forceinline__ float b2f(bf16 x) { return __bfloat162float(x); }
static __device__ __forceinline__ bf16 f2b(float x) { return __float2bfloat16(x); }
static __device__ __forceinline__ unsigned short f2bu(float x) {
    bf16 h = __float2bfloat16(x);
    unsigned short u;
    __builtin_memcpy(&u, &h, 2);
    return u;
}
static __device__ __forceinline__ float bu2f(unsigned short u) {
    unsigned int t = (unsigned int)u << 16;
    float f;
    __builtin_memcpy(&f, &t, 4);
    return f;
}

// global -> LDS direct DMA, 16 B per lane. LDS dest = wave-uniform base + lane*16.
static __device__ __forceinline__ void gl_lds16(const void* g, void* l) {
    __builtin_amdgcn_global_load_lds(
        (const __attribute__((address_space(1))) unsigned int*)g,
        (__attribute__((address_space(3))) unsigned int*)l, 16, 0, 0);
}

// ---------------------------------------------------------------------------
// fp32 -> bf16 conversion, 4 elements/thread.
// ---------------------------------------------------------------------------
__global__ void k_f2b(const float* __restrict__ src, bf16* __restrict__ dst, int n4) {
    int i = blockIdx.x * 256 + threadIdx.x;
    if (i >= n4) return;
    float4 v = ((const float4*)src)[i];
    ushort4 o;
    o.x = f2bu(v.x); o.y = f2bu(v.y); o.z = f2bu(v.z); o.w = f2bu(v.w);
    ((ushort4*)dst)[i] = o;
}

// ---------------------------------------------------------------------------
// fp32 (1024 x 3072) -> bf16 transposed (3072 x 1024).
// ---------------------------------------------------------------------------
__global__ void k_transw(const float* __restrict__ src, bf16* __restrict__ dst) {
    __shared__ float tile[32][33];
    int c0 = blockIdx.x * 32;
    int r0 = blockIdx.y * 32;
    int tx = threadIdx.x, ty = threadIdx.y; // (32,8)
    for (int i = 0; i < 32; i += 8)
        tile[ty + i][tx] = src[(size_t)(r0 + ty + i) * 3072 + c0 + tx];
    __syncthreads();
    for (int i = 0; i < 32; i += 8)
        dst[(size_t)(c0 + ty + i) * 1024 + r0 + tx] = f2b(tile[tx][ty + i]);
}

// ---------------------------------------------------------------------------
// Build A matrices for the wqtw / wkeff GEMMs (64 x 1024 bf16 each).
// ---------------------------------------------------------------------------
__global__ void k_build_sc(const float* __restrict__ pk, const float* __restrict__ wes,
                           bf16* __restrict__ Aq, bf16* __restrict__ Ak) {
    int i = blockIdx.x * 256 + threadIdx.x; // 0..131071
    int half = i >> 16;
    int j = i & 65535;
    int row = j >> 10, d = j & 1023;
    if (half == 0) {
        Aq[j] = (row < 4) ? f2b(wes[(size_t)row * 2048 + d]) : f2b(0.f);
    } else {
        int t = row >> 4, b = (row >> 2) & 3, e = row & 3;
        Ak[j] = f2b(pk[((size_t)t * NB + b) * DD + d] * wes[(size_t)e * 2048 + 1024 + d]);
    }
}

// ---------------------------------------------------------------------------
// Wave-per-output GEMVs (coalesced weight-row reads, shuffle reduce).
// ---------------------------------------------------------------------------
__global__ __launch_bounds__(256) void k_qbase(const float* __restrict__ qenc, const float* __restrict__ w,
                                               const float* __restrict__ b, float* __restrict__ out) {
    int o = blockIdx.x * 4 + (threadIdx.x >> 6);
    int lane = threadIdx.x & 63;
    int n = o >> 2, r = o & 3;
    const float* xr = qenc + (size_t)r * DD;
    const float* wr = w + (size_t)n * DD;
    float s = 0.f;
    for (int d = lane; d < DD; d += 64) s += xr[d] * wr[d];
    for (int off = 32; off; off >>= 1) s += __shfl_down(s, off);
    if (lane == 0) {
        s += b[n];
        out[(size_t)r * DD + n] = s > 0.f ? s : (expf(s) - 1.0f); // ELU
    }
}

__global__ __launch_bounds__(256) void k_cmd(const float* __restrict__ qb, const float* __restrict__ w_qt,
                                             const float* __restrict__ b_qt, float* __restrict__ cmd) {
    int o = blockIdx.x * 4 + (threadIdx.x >> 6);
    int lane = threadIdx.x & 63;
    int r = o & 3, n = (o >> 2) & 1023, t = o >> 12;
    const float* xr = qb + (size_t)r * DD;
    const float* wr = w_qt + ((size_t)t * DD + n) * DD;
    float s = 0.f;
    for (int d = lane; d < DD; d += 64) s += xr[d] * wr[d];
    for (int off = 32; off; off >>= 1) s += __shfl_down(s, off);
    if (lane == 0) cmd[((size_t)t * NB + r) * DD + n] = s + b_qt[t * DD + n];
}

__global__ __launch_bounds__(256) void k_pkpv(const float* __restrict__ cmd,
                                              const float* __restrict__ w_pk, const float* __restrict__ b_pk,
                                              const float* __restrict__ w_pv, const float* __restrict__ b_pv,
                                              float* __restrict__ pk, float* __restrict__ pv) {
    int o = blockIdx.x * 4 + (threadIdx.x >> 6);
    int lane = threadIdx.x & 63;
    int n = o >> 5, half = (o >> 4) & 1, pair = o & 15;
    const float* xr = cmd + (size_t)pair * DD;
    const float* wr = (half ? w_pv : w_pk) + (size_t)n * DD;
    float s = 0.f;
    for (int d = lane; d < DD; d += 64) s += xr[d] * wr[d];
    for (int off = 32; off; off >>= 1) s += __shfl_down(s, off);
    if (lane == 0)
        (half ? pv : pk)[(size_t)pair * DD + n] = s + (half ? b_pv : b_pk)[n];
}

// One wave per output (68 outputs): cq[0..3], ck[0..63].
__global__ void k_consts(const float* __restrict__ b_q, const float* __restrict__ b_k,
                         const float* __restrict__ pk, const float* __restrict__ wes,
                         float* __restrict__ cq, float* __restrict__ ck) {
    int o = blockIdx.x;
    int lane = threadIdx.x;
    float s = 0.f;
    if (o < 4) {
        for (int d = lane; d < 1024; d += 64) s += b_q[d] * wes[(size_t)o * 2048 + d];
    } else {
        int oo = o - 4;
        int t = oo >> 4, b = (oo >> 2) & 3, e = oo & 3;
        for (int d = lane; d < 1024; d += 64)
            s += b_k[d] * pk[((size_t)t * NB + b) * DD + d] * wes[(size_t)e * 2048 + 1024 + d];
    }
    for (int off = 32; off; off >>= 1) s += __shfl_down(s, off);
    if (lane == 0) {
        if (o < 4) cq[o] = s;
        else ck[o - 4] = s;
    }
}

// ---------------------------------------------------------------------------
// qa[m,e], kb[m,e] via collapsed projections: block per row m.
// ---------------------------------------------------------------------------
__global__ __launch_bounds__(256) void k_qakb2(const bf16* __restrict__ ents, const bf16* __restrict__ xc,
                                               const bf16* __restrict__ plpc,
                                               const float* __restrict__ wqtw, const float* __restrict__ wkeff_t,
                                               const float* __restrict__ cq, const float* __restrict__ ck_t,
                                               float* __restrict__ qa, float* __restrict__ kb) {
    __shared__ float red[4][8];
    int m = blockIdx.x;
    int b = m >> 10;
    int t = threadIdx.x;
    float aq[4] = {0.f, 0.f, 0.f, 0.f}, ak[4] = {0.f, 0.f, 0.f, 0.f};
    const bf16* rows[3] = {ents + (size_t)m * DD, xc + (size_t)m * DD, plpc + (size_t)m * DD};
#pragma unroll
    for (int c = 0; c < 3; ++c) {
        const bf16* row = rows[c];
        const float* wq = wqtw + c * 1024;
        const float* wk = wkeff_t + (size_t)b * 4 * 3072 + c * 1024;
        for (int d = t; d < 1024; d += 256) {
            float xv = b2f(row[d]);
#pragma unroll
            for (int e = 0; e < 4; ++e) {
                aq[e] += xv * wq[(size_t)e * 3072 + d];
                ak[e] += xv * wk[(size_t)e * 3072 + d];
            }
        }
    }
#pragma unroll
    for (int e = 0; e < 4; ++e) {
        float v = aq[e];
        for (int o = 32; o; o >>= 1) v += __shfl_down(v, o);
        if ((t & 63) == 0) red[t >> 6][e] = v;
        v = ak[e];
        for (int o = 32; o; o >>= 1) v += __shfl_down(v, o);
        if ((t & 63) == 0) red[t >> 6][e + 4] = v;
    }
    __syncthreads();
    if (t < 8) {
        float s = red[0][t] + red[1][t] + red[2][t] + red[3][t];
        if (t < 4) qa[(size_t)m * 4 + t] = s + cq[t];
        else kb[(size_t)m * 4 + (t - 4)] = s + ck_t[b * 4 + (t - 4)];
    }
}

// ---------------------------------------------------------------------------
// Init: x_ctx = broadcast(initm); xc = initm * mask (per row).
// ---------------------------------------------------------------------------
__global__ void k_init(const bf16* __restrict__ initm_bf, const float* __restrict__ mask,
                       bf16* __restrict__ x_ctx, bf16* __restrict__ xc) {
    int i = blockIdx.x * 256 + threadIdx.x; // uint4 groups, MM*DD/8
    uint4 v = ((const uint4*)initm_bf)[i & 127];
    ((uint4*)x_ctx)[i] = v;
    float mk = mask[i >> 7];
    unsigned short* u = (unsigned short*)&v;
#pragma unroll
    for (int j = 0; j < 8; ++j) u[j] = f2bu(bu2f(u[j]) * mk);
    ((uint4*)xc)[i] = v;
}

// ---------------------------------------------------------------------------
// 64x64-tile GEMM: C[m,n] = sum_c A_c[m,k]*W[n,c*1024+k] (+bias)(+addC)(epilogue)
// BK=64; 4 waves, each 32x32 (2x2 of 16x16x32 MFMA). LDS 16 KB.
// A_c lda=1024; W row-major ldw; C row-major ldc. addC fp32, same index as C.
// mulmode: 0 none, 1 bf16 mul[m*1024+n], 2 f32 mul[(m>>10)*1024+n],
//          3 dual-store: C=val (bf16), C2=val*((f32*)mul)[gm] (bf16).
// ---------------------------------------------------------------------------
__device__ __forceinline__ void gemm_core(
    const bf16* __restrict__ A0, const bf16* __restrict__ A1, const bf16* __restrict__ A2,
    const bf16* __restrict__ W, const float* __restrict__ bias, void* __restrict__ C,
    const void* __restrict__ mul, const float* __restrict__ addC, bf16* __restrict__ C2,
    int mulmode, int storef32, int nchunks, int ldw, int ldc,
    int bm, int bn) {
    __shared__ bf16 sAB[128 * 64]; // A rows 0-63 at [0,4096), B rows 0-63 at [4096,8192)

    const int t = threadIdx.x;
    const int lane = t & 63;
    const int w = t >> 6;
    const int wm = (w & 1) * 32, wn = (w >> 1) * 32;
    const int srow = lane >> 3;      // 0..7
    const int scol = (lane & 7) * 8; // 0..56

    floatx4 acc[2][2];
#pragma unroll
    for (int i = 0; i < 2; ++i)
#pragma unroll
        for (int j = 0; j < 2; ++j) acc[i][j] = (floatx4){0.f, 0.f, 0.f, 0.f};

    const int lrow = lane & 15;
    const int kq = (lane >> 4) * 8;
    const int ktiles = nchunks * 16;

    for (int kt = 0; kt < ktiles; ++kt) {
        const int cidx = kt >> 4;
        const bf16* Ac = (cidx == 0) ? A0 : (cidx == 1 ? A1 : A2);
        const int klocal = (kt & 15) * 64;
        const int kglob = kt * 64;
        // 16 segments of 512 elems (8 rows x 64 cols); wave w stages segs w*4..w*4+3.
#pragma unroll
        for (int s = 0; s < 4; ++s) {
            int c = w * 4 + s;
            if (c < 8) { // A rows c*8..c*8+8
                const bf16* src = Ac + ((size_t)(bm * 64 + c * 8 + srow)) * 1024 + klocal + scol;
                gl_lds16(src, &sAB[c * 512]);
            } else { // B rows (c-8)*8..
                const bf16* src = W + ((size_t)(bn * 64 + (c - 8) * 8 + srow)) * (size_t)ldw + kglob + scol;
                gl_lds16(src, &sAB[c * 512]);
            }
        }
        __syncthreads();
#pragma unroll
        for (int ks = 0; ks < 2; ++ks) {
            const int ko = ks * 32 + kq;
            short8 af[2], bfr[2];
#pragma unroll
            for (int mi = 0; mi < 2; ++mi) af[mi] = *(const short8*)&sAB[(wm + mi * 16 + lrow) * 64 + ko];
#pragma unroll
            for (int ni = 0; ni < 2; ++ni) bfr[ni] = *(const short8*)&sAB[4096 + (wn + ni * 16 + lrow) * 64 + ko];
#pragma unroll
            for (int mi = 0; mi < 2; ++mi)
#pragma unroll
                for (int ni = 0; ni < 2; ++ni)
                    acc[mi][ni] = __builtin_amdgcn_mfma_f32_16x16x32_bf16(af[mi], bfr[ni], acc[mi][ni], 0, 0, 0);
        }
        __syncthreads();
    }

    const int qrow = (lane >> 4) * 4;
#pragma unroll
    for (int mi = 0; mi < 2; ++mi) {
#pragma unroll
        for (int ni = 0; ni < 2; ++ni) {
            int gn = bn * 64 + wn + ni * 16 + lrow;
            float bv = bias ? bias[gn] : 0.f;
#pragma unroll
            for (int r = 0; r < 4; ++r) {
                int gm = bm * 64 + wm + mi * 16 + qrow + r;
                size_t ci = (size_t)gm * (size_t)ldc + gn;
                float val = acc[mi][ni][r] + bv;
                if (addC) val += addC[ci];
                if (mulmode == 1)
                    val *= b2f(((const bf16*)mul)[(size_t)gm * 1024 + gn]);
                else if (mulmode == 2)
                    val *= ((const float*)mul)[(size_t)(gm >> 10) * 1024 + gn];
                if (storef32) {
                    ((float*)C)[ci] = val;
                } else {
                    ((bf16*)C)[ci] = f2b(val);
                    if (mulmode == 3)
                        C2[ci] = f2b(val * ((const float*)mul)[gm]);
                }
            }
        }
    }
}

__global__ __launch_bounds__(256) void k_gemm(
    const bf16* __restrict__ A0, const bf16* __restrict__ A1, const bf16* __restrict__ A2,
    const bf16* __restrict__ W, const float* __restrict__ bias, void* __restrict__ C,
    const void* __restrict__ mul, const float* __restrict__ addC, bf16* __restrict__ C2,
    int mulmode, int storef32, int nchunks, int ldw, int ldc,
    long long sA, long long sW, long long sC) {
    int bz = blockIdx.z;
    const bf16* A0b = A0 + (size_t)bz * sA;
    const bf16* Wb = W + (size_t)bz * sW;
    void* Cb = storef32 ? (void*)((float*)C + (size_t)bz * sC)
                        : (void*)((bf16*)C + (size_t)bz * sC);
    gemm_core(A0b, A1, A2, Wb, bias, Cb, mul, addC, C2, mulmode, storef32, nchunks, ldw, ldc,
              blockIdx.x, blockIdx.y);
}

// ---------------------------------------------------------------------------
// v (B,N,D) -> vT (B,D,N)
// ---------------------------------------------------------------------------
__global__ void k_transpose(const bf16* __restrict__ v, bf16* __restrict__ vT) {
    __shared__ bf16 tile[32][33];
    int b = blockIdx.z;
    int n0 = blockIdx.x * 32, d0 = blockIdx.y * 32;
    int tx = threadIdx.x, ty = threadIdx.y; // (32,8)
    for (int i = 0; i < 32; i += 8)
        tile[ty + i][tx] = v[((size_t)b * NN + n0 + ty + i) * DD + d0 + tx];
    __syncthreads();
    for (int i = 0; i < 32; i += 8)
        vT[((size_t)b * DD + d0 + ty + i) * NN + n0 + tx] = tile[tx][ty + i];
}

// ---------------------------------------------------------------------------
// Edge scores + masked softmax: one block per (b,i) row.
// ---------------------------------------------------------------------------
__global__ __launch_bounds__(256) void k_attn(const int* __restrict__ adj, const float* __restrict__ qa,
                                              const float* __restrict__ kb, const int* __restrict__ typesPtr,
                                              bf16* __restrict__ prob) {
    __shared__ float lg[NN];
    __shared__ float red[4];
    __shared__ float red2[4];
    int m = blockIdx.x;
    int b = m >> 10;
    int t = threadIdx.x;
    int types = typesPtr[0];
    float qa4[4];
#pragma unroll
    for (int e = 0; e < 4; ++e) qa4[e] = qa[(size_t)m * 4 + e];
    const int* arow = adj + (size_t)m * NN;
    const float* kbb = kb + (size_t)(b << 10) * 4;

    float lmax = -3.0e38f;
    for (int j = t; j < NN; j += 256) {
        int a = arow[j];
        float l;
        if (a == 0) {
            l = -9.0e15f;
        } else if ((types >> a) & 1) {
            float s = qa4[a - 1] + kbb[(size_t)j * 4 + (a - 1)];
            l = s > 0.f ? s : 0.2f * s;
        } else {
            l = 0.f;
        }
        lg[j] = l;
        lmax = fmaxf(lmax, l);
    }
    for (int o = 32; o > 0; o >>= 1) lmax = fmaxf(lmax, __shfl_down(lmax, o));
    if ((t & 63) == 0) red[t >> 6] = lmax;
    __syncthreads();
    lmax = fmaxf(fmaxf(red[0], red[1]), fmaxf(red[2], red[3]));

    float lsum = 0.f;
    for (int j = t; j < NN; j += 256) {
        float ex = expf(lg[j] - lmax);
        lg[j] = ex;
        lsum += ex;
    }
    for (int o = 32; o > 0; o >>= 1) lsum += __shfl_down(lsum, o);
    if ((t & 63) == 0) red2[t >> 6] = lsum;
    __syncthreads();
    lsum = red2[0] + red2[1] + red2[2] + red2[3];
    float inv = 1.0f / lsum;

    bf16* prow = prob + (size_t)m * NN;
    for (int j = t; j < NN; j += 256) prow[j] = f2b(lg[j] * inv);
}

// ---------------------------------------------------------------------------
extern "C" void kernel_launch(void* const* d_in, const int* in_sizes, int n_in,
                              void* d_out, int out_size, void* d_ws, size_t ws_size,
                              hipStream_t stream) {
    const float* ents = (const float*)d_in[0];
    const float* mask = (const float*)d_in[1];
    const float* qenc = (const float*)d_in[2];
    const int* adj = (const int*)d_in[3];
    const int* types = (const int*)d_in[4];
    const float* initm = (const float*)d_in[5];
    const float* w_qin = (const float*)d_in[6];
    const float* b_qin = (const float*)d_in[7];
    const float* w_qt = (const float*)d_in[8];
    const float* b_qt = (const float*)d_in[9];
    const float* w_pl = (const float*)d_in[10];
    const float* b_pl = (const float*)d_in[11];
    const float* w_pc = (const float*)d_in[12];
    const float* b_pc = (const float*)d_in[13];
    const float* w_q = (const float*)d_in[14];
    const float* b_q = (const float*)d_in[15];
    const float* w_k = (const float*)d_in[16];
    const float* b_k = (const float*)d_in[17];
    const float* w_v = (const float*)d_in[18];
    const float* b_v = (const float*)d_in[19];
    const float* w_pk = (const float*)d_in[20];
    const float* b_pk = (const float*)d_in[21];
    const float* w_pv = (const float*)d_in[22];
    const float* b_pv = (const float*)d_in[23];
    const float* wes = (const float*)d_in[24];
    const float* w_mu = (const float*)d_in[25];
    const float* b_mu = (const float*)d_in[26];
    const float* w_cb = (const float*)d_in[27];
    const float* b_cb = (const float*)d_in[28];
    (void)in_sizes; (void)n_in; (void)out_size; (void)ws_size;

    char* p = (char*)d_ws;
    auto carve = [&](size_t bytes) {
        char* r = p;
        p += (bytes + 255) & ~(size_t)255;
        return r;
    };
    // fp32 smalls
    float* q_base = (float*)carve((size_t)NB * DD * 4);
    float* cmd = (float*)carve((size_t)NT_ITER * NB * DD * 4);
    float* pk = (float*)carve((size_t)NT_ITER * NB * DD * 4);
    float* pv = (float*)carve((size_t)NT_ITER * NB * DD * 4);
    float* qa = (float*)carve((size_t)MM * 4 * 4);
    float* kb = (float*)carve((size_t)MM * 4 * 4);
    float* wqtw = (float*)carve((size_t)64 * 3072 * 4);  // rows 0..3 used
    float* wkeff = (float*)carve((size_t)64 * 3072 * 4); // row t*16+b*4+e
    float* cq = (float*)carve(4 * 4);
    float* ck = (float*)carve(64 * 4);
    float* vent = (float*)carve((size_t)MM * DD * 4); // ents @ Wv[:, :D]^T (fp32)
    // bf16 copies
    bf16* initm_bf = (bf16*)carve((size_t)DD * 2);
    bf16* ents_bf = (bf16*)carve((size_t)MM * DD * 2);
    bf16* wpl_bf = (bf16*)carve((size_t)DD * DD * 2);
    bf16* wpc_bf = (bf16*)carve((size_t)DD * DD * 2);
    bf16* wv_bf = (bf16*)carve((size_t)DD * 3 * DD * 2);
    bf16* wmu_bf = (bf16*)carve((size_t)DD * 2 * DD * 2);
    bf16* wcb_bf = (bf16*)carve((size_t)DD * 2 * DD * 2);
    bf16* wqT_bf = (bf16*)carve((size_t)3 * DD * DD * 2); // w_q^T (3072 x 1024)
    bf16* wkT_bf = (bf16*)carve((size_t)3 * DD * DD * 2); // w_k^T
    bf16* Aq = (bf16*)carve((size_t)64 * DD * 2);
    bf16* Ak = (bf16*)carve((size_t)64 * DD * 2);
    // bf16 activations
    bf16* x_ctx = (bf16*)carve((size_t)MM * DD * 2);
    bf16* xc = (bf16*)carve((size_t)MM * DD * 2);
    bf16* pl = (bf16*)carve((size_t)MM * DD * 2);
    bf16* plpc = (bf16*)carve((size_t)MM * DD * 2); // dead after k_qakb2 -> reused as vT
    bf16* vbuf = (bf16*)carve((size_t)MM * DD * 2);
    bf16* msg = (bf16*)carve((size_t)MM * DD * 2);
    bf16* prob = (bf16*)carve((size_t)NB * NN * NN * 2);
    bf16* vT = plpc;

    const dim3 blk(256);
    const dim3 g64(64, 16, 1);   // M=4096, N=1024, 64x64 tiles -> 1024 blocks
    const dim3 gMsg(16, 16, NB); // per-batch M=1024 -> 1024 blocks
    const dim3 gPre(1, 48, 1);   // M=64, N=3072 precompute GEMMs

    // fp32 -> bf16 conversions (once per launch)
    k_f2b<<<1, blk, 0, stream>>>(initm, initm_bf, DD / 4);
    k_f2b<<<4096, blk, 0, stream>>>(ents, ents_bf, MM * DD / 4);
    k_f2b<<<1024, blk, 0, stream>>>(w_pl, wpl_bf, DD * DD / 4);
    k_f2b<<<1024, blk, 0, stream>>>(w_pc, wpc_bf, DD * DD / 4);
    k_f2b<<<3072, blk, 0, stream>>>(w_v, wv_bf, DD * 3 * DD / 4);
    k_f2b<<<2048, blk, 0, stream>>>(w_mu, wmu_bf, DD * 2 * DD / 4);
    k_f2b<<<2048, blk, 0, stream>>>(w_cb, wcb_bf, DD * 2 * DD / 4);
    k_transw<<<dim3(96, 32), dim3(32, 8), 0, stream>>>(w_q, wqT_bf);
    k_transw<<<dim3(96, 32), dim3(32, 8), 0, stream>>>(w_k, wkT_bf);

    k_qbase<<<1024, blk, 0, stream>>>(qenc, w_qin, b_qin, q_base);
    k_cmd<<<4096, blk, 0, stream>>>(q_base, w_qt, b_qt, cmd);
    k_pkpv<<<8192, blk, 0, stream>>>(cmd, w_pk, b_pk, w_pv, b_pv, pk, pv);
    k_init<<<2048, blk, 0, stream>>>(initm_bf, mask, x_ctx, xc);

    // q/k collapse precompute: A matrices, consts, then two tiny MFMA GEMMs.
    k_build_sc<<<512, blk, 0, stream>>>(pk, wes, Aq, Ak);
    k_consts<<<68, 64, 0, stream>>>(b_q, b_k, pk, wes, cq, ck);
    // wqtw(64x3072,f32) = Aq @ wqT^T ; wkeff = Ak @ wkT^T
    k_gemm<<<gPre, blk, 0, stream>>>(Aq, nullptr, nullptr, wqT_bf, nullptr, wqtw,
                                     nullptr, nullptr, nullptr, 0, 1, 1, 1024, 3072, 0, 0, 0);
    k_gemm<<<gPre, blk, 0, stream>>>(Ak, nullptr, nullptr, wkT_bf, nullptr, wkeff,
                                     nullptr, nullptr, nullptr, 0, 1, 1, 1024, 3072, 0, 0, 0);

    // Loop-invariant GEMMs:
    // pl = ents @ w_pl.T + b_pl
    k_gemm<<<g64, blk, 0, stream>>>(ents_bf, nullptr, nullptr, wpl_bf, b_pl, pl,
                                    nullptr, nullptr, nullptr, 0, 0, 1, 1024, 1024, 0, 0, 0);
    // vent = ents @ w_v[:, :D].T  (fp32, no bias/mul)
    k_gemm<<<g64, blk, 0, stream>>>(ents_bf, nullptr, nullptr, wv_bf, nullptr, vent,
                                    nullptr, nullptr, nullptr, 0, 1, 1, 3072, 1024, 0, 0, 0);

    for (int t = 0; t < NT_ITER; ++t) {
        // plpc = (xc @ w_pc.T + b_pc) * pl
        k_gemm<<<g64, blk, 0, stream>>>(xc, nullptr, nullptr, wpc_bf, b_pc, plpc,
                                        pl, nullptr, nullptr, 1, 0, 1, 1024, 1024, 0, 0, 0);
        // v = (vent + [xc, plpc] @ w_v[:, D:].T + b_v) * pv[t,b,:]
        k_gemm<<<g64, blk, 0, stream>>>(xc, plpc, nullptr, wv_bf + 1024, b_v, vbuf,
                                        pv + (size_t)t * NB * DD, vent, nullptr, 2, 0, 2, 3072, 1024, 0, 0, 0);
        // qa/kb via collapsed projections
        k_qakb2<<<4096, blk, 0, stream>>>(ents_bf, xc, plpc,
                                          wqtw, wkeff + (size_t)t * 16 * 3072,
                                          cq, ck + t * 16, qa, kb);
        k_transpose<<<dim3(32, 32, NB), dim3(32, 8), 0, stream>>>(vbuf, vT);
        k_attn<<<4096, blk, 0, stream>>>(adj, qa, kb, types, prob);
        // message[b] = prob[b] @ v[b]  (NT with W = vT[b])
        k_gemm<<<gMsg, blk, 0, stream>>>(prob, nullptr, nullptr, vT, nullptr, msg,
                                         nullptr, nullptr, nullptr, 0, 0, 1, 1024, 1024,
                                         (long long)NN * NN, (long long)DD * NN, (long long)NN * DD);
        // x_ctx = [xc, msg] @ w_mu.T + b_mu ; xc = x_ctx * mask (fused, mulmode 3)
        k_gemm<<<g64, blk, 0, stream>>>(xc, msg, nullptr, wmu_bf, b_mu, x_ctx,
                                        mask, nullptr, xc, 3, 0, 2, 2048, 1024, 0, 0, 0);
    }
    // out = [ents, x_ctx] @ w_cb.T + b_cb  (fp32 store)
    k_gemm<<<g64, blk, 0, stream>>>(ents_bf, x_ctx, nullptr, wcb_bf, b_cb, (float*)d_out,
                                    nullptr, nullptr, nullptr, 0, 1, 2, 2048, 1024, 0, 0, 0);
}